// Round 2
// baseline (6048.751 us; speedup 1.0000x reference)
//
#include <hip/hip_runtime.h>
#include <math.h>

// Problem constants
#define NCLS 19
#define FDIM 256
#define DDIR 1024
#define NPIX 8192
#define KPAD 768            // per-class compacted-column padding (max n_c ~ 500)
#define NSWEEP 5
#define NROUND 255
#define NSTEP (NSWEEP*NROUND)
#define NPAIR 128
#define TRI_N 32896         // 256*257/2  (exact multiple of 32 -> swizzle-safe)
#define NOFF 8128           // 128*127/2 off-diagonal group pairs (s1<s2)
#define NSEG 32             // 8192 / 256 label segments
#define VST 66              // replay V-state row stride (64 + 2 pad)
#define FLAGSTRIDE 16       // pad step-flags to 64B lines

// ---- device-global workspace ----
__device__ float g_cntf[NCLS];
__device__ float g_ns[NCLS];
__device__ float g_mu[NCLS][FDIM];
__device__ int   g_rank[NPIX];
__device__ int   g_segcnt[NSEG][NCLS];
__device__ int   g_segoff[NSEG][NCLS];
__device__ float g_X[NCLS][FDIM][KPAD];
__device__ float g_cov[NCLS][FDIM][FDIM];
__device__ unsigned long long g_rotlog[NCLS][NSTEP][NPAIR];  // packed (c,s)
__device__ int   g_step[NCLS*FLAGSTRIDE];
__device__ float g_eval[NCLS][FDIM];
__device__ float g_W[NCLS][FDIM][FDIM];
__device__ float g_M[NCLS][DDIR][FDIM];
__device__ float g_mom[NCLS][DDIR][4];

union PackCS { float2 f; unsigned long long u; };
union PackF  { float f; unsigned int u; };

// round-robin tournament pairing: 255 fixed, 0..254 rotate
__device__ __forceinline__ void get_pair(int r, int s, int& p, int& q) {
    int a, b;
    if (s == 0) { a = NROUND; b = r; }
    else {
        a = r + s; if (a >= NROUND) a -= NROUND;
        b = r - s; if (b < 0) b += NROUND;
    }
    p = min(a, b); q = max(a, b);
}

__device__ __forceinline__ int tidx(int i, int j) { return ((i*(i+1))>>1) + j; } // i>=j
__device__ __forceinline__ int tidx2(int a, int b) { return a >= b ? tidx(a,b) : tidx(b,a); }

// Bank-decorrelating swizzle for the triangular buffer. The quadratic
// triangular addressing makes consecutive-lane address deltas equal p1+2,
// which periodically aligns to multiples of 32 banks -> systematic
// conflicts (R1: 6.7e7 conflict cycles). XOR address bits [5:10)^[10:15)
// into the bank bits. Bijective within each aligned 32-dword block;
// TRI_N = 1028*32 exactly, so no out-of-bounds remap.
__device__ __forceinline__ int swz(int L) {
    return L ^ (((L >> 5) ^ (L >> 10)) & 31);
}

// ---- K0: zero compacted buffer + flags + segment counters ----
__global__ __launch_bounds__(1024) void k_zero() {
    int idx = blockIdx.x*blockDim.x + threadIdx.x;
    const int total = NCLS*FDIM*KPAD;
    float* x = &g_X[0][0][0];
    for (int i = idx; i < total; i += gridDim.x*blockDim.x) x[i] = 0.f;
    if (idx < NCLS*FLAGSTRIDE) g_step[idx] = 0;
    if (idx < NSEG*NCLS) (&g_segcnt[0][0])[idx] = 0;
}

// ---- K1: per-class sums per feature + counts; writes mu/ns directly ----
__global__ void k_sums(const float* __restrict__ feat, const int* __restrict__ lab) {
    __shared__ float acc[NCLS][256];
    __shared__ float cnt[NCLS][256];
    int t = threadIdx.x;
    int f = blockIdx.x;
    for (int c = 0; c < NCLS; ++c) { acc[c][t] = 0.f; cnt[c][t] = 0.f; }
    for (int j = 0; j < NPIX/256; ++j) {
        int n = t + 256*j;
        int b = n >> 12, hw = n & 4095;
        float v = feat[(size_t)b*1048576 + (size_t)f*4096 + hw];
        int c = lab[n];
        acc[c][t] += v;
        cnt[c][t] += 1.f;
    }
    __syncthreads();
    for (int off = 128; off > 0; off >>= 1) {
        if (t < off)
            for (int c = 0; c < NCLS; ++c) {
                acc[c][t] += acc[c][t+off];
                cnt[c][t] += cnt[c][t+off];
            }
        __syncthreads();
    }
    if (t < NCLS) {
        float ns = fmaxf(cnt[t][0], 1.f);
        g_mu[t][f] = acc[t][0] / ns;      // identical operands/order as old musetup
        if (f == 0) { g_cntf[t] = cnt[t][0]; g_ns[t] = ns; }
    }
}

// ---- K3a: deterministic per-segment rank + per-segment class counts ----
__global__ void k_rank(const int* __restrict__ lab) {
    __shared__ int sl[256];
    int seg = blockIdx.x, t = threadIdx.x;
    int n = seg*256 + t;
    int c = lab[n];
    sl[t] = c;
    __syncthreads();
    int rnk = 0, tot = 0;
    for (int i = 0; i < 256; ++i) {
        int e = sl[i];
        if (e == c) { tot += 1; if (i < t) rnk += 1; }
    }
    g_rank[n] = rnk;
    if (rnk == 0) g_segcnt[seg][c] = tot;
}

// ---- K3b: exclusive scan of segment counts per class ----
__global__ void k_segscan() {
    int c = threadIdx.x;
    if (c < NCLS) {
        int run = 0;
        for (int s = 0; s < NSEG; ++s) {
            g_segoff[s][c] = run;
            run += g_segcnt[s][c];
        }
    }
}

// ---- K4: scatter centered features into per-class compacted matrix ----
__global__ void k_scatter(const float* __restrict__ feat, const int* __restrict__ lab) {
    int n = blockIdx.x*256 + threadIdx.x;
    int g = blockIdx.y;
    int c = lab[n];
    int pos = g_segoff[n >> 8][c] + g_rank[n];
    float v = feat[(size_t)(n>>12)*1048576 + (size_t)g*4096 + (n&4095)] - g_mu[c][g];
    g_X[c][g][pos] = v;
}

// ---- K5: cov = (Xc Xc^T)/ns ----
__global__ void k_covgemm() {
    int cls = blockIdx.z, ti = blockIdx.y, tj = blockIdx.x;
    __shared__ float At[64][17], Bt[64][17];
    int t = threadIdx.x, tx = t & 15, ty = t >> 4;
    float accv[4][4] = {};
    for (int k0 = 0; k0 < KPAD; k0 += 16) {
        #pragma unroll
        for (int l = 0; l < 4; ++l) {
            int idx = t*4 + l;
            int row = idx >> 4, col = idx & 15;
            At[row][col] = g_X[cls][ti*64+row][k0+col];
            Bt[row][col] = g_X[cls][tj*64+row][k0+col];
        }
        __syncthreads();
        #pragma unroll
        for (int kk = 0; kk < 16; ++kk) {
            float a[4], b[4];
            #pragma unroll
            for (int i = 0; i < 4; ++i) a[i] = At[ty*4+i][kk];
            #pragma unroll
            for (int j = 0; j < 4; ++j) b[j] = Bt[tx*4+j][kk];
            #pragma unroll
            for (int i = 0; i < 4; ++i)
                #pragma unroll
                for (int j = 0; j < 4; ++j) accv[i][j] += a[i]*b[j];
        }
        __syncthreads();
    }
    float invns = 1.f / g_ns[cls];
    #pragma unroll
    for (int i = 0; i < 4; ++i)
        #pragma unroll
        for (int j = 0; j < 4; ++j)
            g_cov[cls][ti*64+ty*4+i][tj*64+tx*4+j] = accv[i][j]*invns;
}

// ---- K6: FUSED eigensolver (producer = Jacobi, consumer = V accumulation
//          + fused eigen-sort / W write) ----
__global__ __launch_bounds__(1024) void k_eigen() {
    extern __shared__ float smem[];
    int t = threadIdx.x;

    if (blockIdx.x < NCLS) {
        // ================= Jacobi producer =================
        float2* pcs = (float2*)smem;  // 128 packed (c,s) -> same 256-float footprint
        float* tri  = smem + 256;     // TRI_N floats (bank-swizzled layout)
        int cls = blockIdx.x;

        for (int L = t; L < TRI_N; L += 1024) {
            int i = (int)((sqrtf(8.f*L+1.f)-1.f)*0.5f);
            while ((i+1)*(i+2)/2 <= L) ++i;
            while (i*(i+1)/2 > L) --i;
            int j = L - i*(i+1)/2;
            tri[swz(L)] = g_cov[cls][i][j];
        }

        // Fixed-sA group mapping: thread rotates its own pair-index sA against
        // 8 partners sB = (sA + d) & 127 with d = 8k + h + 1 in 1..64.
        // Coverage: d=1..63 over all 128 origins covers each unordered group
        // once; d=64 (k==7,h==7) restricted to sA<64. Total = 8064+64 = 8128.
        // Skip pattern is wave-uniform (wave 15 skips k=7 entirely).
        const int sA = t & 127;
        const int h  = t >> 7;
        const bool k7ok = (h != 7) || (sA < 64);
        int sB[8];
        #pragma unroll
        for (int k = 0; k < 8; ++k) sB[k] = (sA + 8*k + h + 1) & 127;

        // Incremental round-robin state: for pair index s, a=(r+s)%255 (or 255
        // fixed when s==0), b=(r-s)%255; both advance +1 mod 255 per step.
        const bool zA = (sA == 0);
        int aA = zA ? NROUND : sA;
        int bA = zA ? 0 : NROUND - sA;
        int aB[8], bB[8];
        unsigned zBm = 0;
        #pragma unroll
        for (int k = 0; k < 8; ++k) {
            bool z = (sB[k] == 0);
            if (z) zBm |= 1u << k;
            aB[k] = z ? NROUND : sB[k];
            bB[k] = z ? 0 : NROUND - sB[k];
        }
        __syncthreads();

        for (int step = 0; step < NSTEP; ++step) {
            int r = step % NROUND;
            if (t < NPAIR) {
                int p, q; get_pair(r, t, p, q);
                float app = tri[swz(tidx(p,p))], aqq = tri[swz(tidx(q,q))];
                float apq = tri[swz(tidx(q,p))];
                float c = 1.f, s = 0.f;
                if (fabsf(apq) > 1e-30f) {
                    float theta = (aqq - app) / (2.f*apq);
                    float tt = 1.f/(fabsf(theta) + sqrtf(theta*theta + 1.f));
                    if (theta < 0.f) tt = -tt;
                    c = 1.f/sqrtf(tt*tt + 1.f);
                    s = tt*c;
                }
                // store rotlog early: maximizes drain time before 2nd barrier
                PackCS pk; pk.f = make_float2(c, s);
                __hip_atomic_store(&g_rotlog[cls][step][t], pk.u,
                                   __ATOMIC_RELAXED, __HIP_MEMORY_SCOPE_AGENT);
                pcs[t] = make_float2(c, s);
                // diagonal 2x2 update (hazard-free: no off-diag group touches these)
                float napp = c*c*app - 2.f*c*s*apq + s*s*aqq;
                float naqq = s*s*app + 2.f*c*s*apq + c*c*aqq;
                tri[swz(tidx(p,p))] = napp;
                tri[swz(tidx(q,q))] = naqq;
                tri[swz(tidx(q,p))] = 0.f;
            }
            __syncthreads();   // pcs + diag updates visible

            int pA = min(aA, bA), qA = max(aA, bA);
            float2 csA = pcs[sA];
            #pragma unroll
            for (int k = 0; k < 8; ++k) {
                if (k == 7 && !k7ok) continue;
                int pB = min(aB[k], bB[k]), qB = max(aB[k], bB[k]);
                float2 csB = pcs[sB[k]];
                // preserve original role order: smaller pair index acts on rows
                bool sw = sB[k] < sA;
                int p1 = sw ? pB : pA, q1 = sw ? qB : qA;
                int p2 = sw ? pA : pB, q2 = sw ? qA : qB;
                float c1 = sw ? csB.x : csA.x, sv1 = sw ? csB.y : csA.y;
                float c2 = sw ? csA.x : csB.x, sv2 = sw ? csA.y : csB.y;
                int i00 = swz(tidx2(p1,p2)), i01 = swz(tidx2(p1,q2));
                int i10 = swz(tidx2(q1,p2)), i11 = swz(tidx2(q1,q2));
                float B00 = tri[i00], B01 = tri[i01];
                float B10 = tri[i10], B11 = tri[i11];
                float X00 = c1*B00 - sv1*B10, X01 = c1*B01 - sv1*B11;
                float X10 = sv1*B00 + c1*B10, X11 = sv1*B01 + c1*B11;
                tri[i00] = c2*X00 - sv2*X01;
                tri[i01] = sv2*X00 + c2*X01;
                tri[i10] = c2*X10 - sv2*X11;
                tri[i11] = sv2*X10 + c2*X11;
            }
            // advance round-robin state (+1 mod 255; fixed slot stays at 255)
            bA = (bA+1 == NROUND) ? 0 : bA+1;
            if (!zA) aA = (aA+1 == NROUND) ? 0 : aA+1;
            #pragma unroll
            for (int k = 0; k < 8; ++k) {
                bB[k] = (bB[k]+1 == NROUND) ? 0 : bB[k]+1;
                if (!(zBm & (1u<<k))) aB[k] = (aB[k]+1 == NROUND) ? 0 : aB[k]+1;
            }
            __syncthreads();   // drains rotlog store (vmcnt0) + all LDS
            if (t == 0) {
                __hip_atomic_store(&g_step[cls*FLAGSTRIDE], step+1,
                                   __ATOMIC_RELAXED, __HIP_MEMORY_SCOPE_AGENT);
            }
        }
        // publish eigenvalues (agent-scope -> LLC) then release final flag
        for (int f = t; f < FDIM; f += 1024) {
            PackF pf; pf.f = tri[swz(tidx(f,f))];
            __hip_atomic_store((unsigned int*)&g_eval[cls][f], pf.u,
                               __ATOMIC_RELAXED, __HIP_MEMORY_SCOPE_AGENT);
        }
        __syncthreads();       // drains eval stores
        if (t == 0) {
            __hip_atomic_store(&g_step[cls*FLAGSTRIDE], NSTEP+1,
                               __ATOMIC_RELAXED, __HIP_MEMORY_SCOPE_AGENT);
        }
    } else {
        // ======= eigenvector consumer (+ fused sort / W write) =======
        float2* lcs = (float2*)smem;            // 128 packed (c,s)
        float* st = smem + 256;                 // 256 x VST state (64 V-columns)
        float* evbuf = smem + 256 + 256*VST;    // 256 eigenvalues (reuse tail)
        int*   rkbuf = (int*)(evbuf + 256);     // 256 ranks
        int rb = blockIdx.x - NCLS;
        int cls = rb >> 2;
        int ibase = (rb & 3) * 64;

        for (int idx = t; idx < 256*64; idx += 1024) {
            int p = idx >> 6, col = idx & 63;
            st[p*VST + col] = (p == ibase + col) ? 1.f : 0.f;
        }

        int s0 = t >> 5;
        int cp = t & 31;
        // incremental pair state for s_w = s0 + 32w
        int aw[4], bw[4];
        unsigned zwm = 0;
        #pragma unroll
        for (int w = 0; w < 4; ++w) {
            int s = s0 + 32*w;
            bool z = (s == 0);
            if (z) zwm |= 1u << w;
            aw[w] = z ? NROUND : s;
            bw[w] = z ? 0 : NROUND - s;
        }
        __syncthreads();

        for (int step = 0; step < NSTEP; ++step) {
            if (t == 0) {
                while (__hip_atomic_load(&g_step[cls*FLAGSTRIDE], __ATOMIC_RELAXED,
                                         __HIP_MEMORY_SCOPE_AGENT) <= step)
                    __builtin_amdgcn_s_sleep(2);
            }
            __syncthreads();
            if (t < NPAIR) {
                PackCS pk;
                pk.u = __hip_atomic_load(&g_rotlog[cls][step][t],
                                         __ATOMIC_RELAXED, __HIP_MEMORY_SCOPE_AGENT);
                lcs[t] = pk.f;
            }
            __syncthreads();
            float2 xv[4], yv[4];
            float cv[4], sv[4];
            int pa[4], qa[4];
            #pragma unroll
            for (int w = 0; w < 4; ++w) {
                float2 cs = lcs[s0 + 32*w];
                cv[w] = cs.x; sv[w] = cs.y;
                pa[w] = min(aw[w], bw[w]); qa[w] = max(aw[w], bw[w]);
                xv[w] = *(float2*)&st[pa[w]*VST + 2*cp];
                yv[w] = *(float2*)&st[qa[w]*VST + 2*cp];
            }
            #pragma unroll
            for (int w = 0; w < 4; ++w) {
                float2 nx, ny;
                nx.x = cv[w]*xv[w].x - sv[w]*yv[w].x;
                nx.y = cv[w]*xv[w].y - sv[w]*yv[w].y;
                ny.x = sv[w]*xv[w].x + cv[w]*yv[w].x;
                ny.y = sv[w]*xv[w].y + cv[w]*yv[w].y;
                *(float2*)&st[pa[w]*VST + 2*cp] = nx;
                *(float2*)&st[qa[w]*VST + 2*cp] = ny;
            }
            #pragma unroll
            for (int w = 0; w < 4; ++w) {
                bw[w] = (bw[w]+1 == NROUND) ? 0 : bw[w]+1;
                if (!(zwm & (1u<<w))) aw[w] = (aw[w]+1 == NROUND) ? 0 : aw[w]+1;
            }
        }
        // wait for eigenvalues, rank them (identical comparator to old k_sort)
        if (t == 0) {
            while (__hip_atomic_load(&g_step[cls*FLAGSTRIDE], __ATOMIC_RELAXED,
                                     __HIP_MEMORY_SCOPE_AGENT) <= NSTEP)
                __builtin_amdgcn_s_sleep(2);
        }
        __syncthreads();
        if (t < 256) {
            PackF pf;
            pf.u = __hip_atomic_load((unsigned int*)&g_eval[cls][t],
                                     __ATOMIC_RELAXED, __HIP_MEMORY_SCOPE_AGENT);
            evbuf[t] = pf.f;
        }
        __syncthreads();
        if (t < 256) {
            float mine = evbuf[t];
            int r = 0;
            for (int f = 0; f < 256; ++f) {
                float o = evbuf[f];
                if (o > mine || (o == mine && f < t)) ++r;
            }
            rkbuf[t] = r;
        }
        __syncthreads();
        for (int idx = t; idx < 256*32; idx += 1024) {
            int f = idx >> 5, c2 = idx & 31;
            float2 v = *(float2*)&st[f*VST + 2*c2];
            *(float2*)&g_W[cls][rkbuf[f]][ibase + 2*c2] = v;
        }
    }
}

// ---- K10: M[c] = proj @ W[c]   (D x F) ----
__global__ void k_mgemm(const float* __restrict__ pm) {
    int cls = blockIdx.z, dt = blockIdx.y, gt = blockIdx.x;
    __shared__ float At[64][17], Bt[16][65];
    int t = threadIdx.x, tx = t & 15, ty = t >> 4;
    float accv[4][4] = {};
    for (int k0 = 0; k0 < FDIM; k0 += 16) {
        #pragma unroll
        for (int l = 0; l < 4; ++l) {
            int idx = t*4 + l;
            int row = idx >> 4, col = idx & 15;
            At[row][col] = pm[(size_t)(dt*64+row)*FDIM + k0 + col];
        }
        #pragma unroll
        for (int l = 0; l < 4; ++l) {
            int idx = t*4 + l;
            int row = idx >> 6, col = idx & 63;
            Bt[row][col] = g_W[cls][k0+row][gt*64+col];
        }
        __syncthreads();
        #pragma unroll
        for (int kk = 0; kk < 16; ++kk) {
            float a[4], b[4];
            #pragma unroll
            for (int i = 0; i < 4; ++i) a[i] = At[ty*4+i][kk];
            #pragma unroll
            for (int j = 0; j < 4; ++j) b[j] = Bt[kk][tx*4+j];
            #pragma unroll
            for (int i = 0; i < 4; ++i)
                #pragma unroll
                for (int j = 0; j < 4; ++j) accv[i][j] += a[i]*b[j];
        }
        __syncthreads();
    }
    #pragma unroll
    for (int i = 0; i < 4; ++i)
        #pragma unroll
        for (int j = 0; j < 4; ++j)
            g_M[cls][dt*64+ty*4+i][gt*64+tx*4+j] = accv[i][j];
}

// ---- K11: fv = M[c] @ Xc, accumulate moments m1..m4 over columns ----
__global__ void k_fvmom() {
    int cls = blockIdx.y, dt = blockIdx.x;
    __shared__ float Mt[64][17], Xt[16][65];
    __shared__ float red[64][16];
    int t = threadIdx.x, tx = t & 15, ty = t >> 4;
    float mm[4][4] = {};
    for (int kt = 0; kt < KPAD; kt += 64) {
        float accv[4][4] = {};
        for (int g0 = 0; g0 < FDIM; g0 += 16) {
            #pragma unroll
            for (int l = 0; l < 4; ++l) {
                int idx = t*4 + l;
                int row = idx >> 4, col = idx & 15;
                Mt[row][col] = g_M[cls][dt*64+row][g0+col];
            }
            #pragma unroll
            for (int l = 0; l < 4; ++l) {
                int idx = t*4 + l;
                int row = idx >> 6, col = idx & 63;
                Xt[row][col] = g_X[cls][g0+row][kt+col];
            }
            __syncthreads();
            #pragma unroll
            for (int kk = 0; kk < 16; ++kk) {
                float a[4], b[4];
                #pragma unroll
                for (int i = 0; i < 4; ++i) a[i] = Mt[ty*4+i][kk];
                #pragma unroll
                for (int j = 0; j < 4; ++j) b[j] = Xt[kk][tx*4+j];
                #pragma unroll
                for (int i = 0; i < 4; ++i)
                    #pragma unroll
                    for (int j = 0; j < 4; ++j) accv[i][j] += a[i]*b[j];
            }
            __syncthreads();
        }
        #pragma unroll
        for (int i = 0; i < 4; ++i)
            #pragma unroll
            for (int j = 0; j < 4; ++j) {
                float v = accv[i][j], v2 = v*v;
                mm[0][i] += v; mm[1][i] += v2; mm[2][i] += v2*v; mm[3][i] += v2*v2;
            }
    }
    #pragma unroll
    for (int m = 0; m < 4; ++m) {
        __syncthreads();
        #pragma unroll
        for (int i = 0; i < 4; ++i) red[ty*4+i][tx] = mm[m][i];
        __syncthreads();
        if (t < 64) {
            float s = 0.f;
            #pragma unroll
            for (int x = 0; x < 16; ++x) s += red[t][x];
            g_mom[cls][dt*64 + t][m] = s;
        }
    }
}

// ---- K12: kurtosis, clip, weighted mean -> loss ----
__global__ __launch_bounds__(1024) void k_loss(float* __restrict__ out) {
    __shared__ float red[1024];
    int t = threadIdx.x;
    float sum = 0.f;
    for (int id = t; id < NCLS*DDIR; id += 1024) {
        int c = id >> 10, d = id & 1023;
        float cntv = g_cntf[c];
        if (cntv > 0.f) {
            float invns = 1.f / g_ns[c];
            float m1 = g_mom[c][d][0]*invns;
            float m2 = g_mom[c][d][1]*invns;
            float m3 = g_mom[c][d][2]*invns;
            float m4 = g_mom[c][d][3]*invns;
            float var = fmaxf(m2 - m1*m1, 1e-16f);
            float m4c = -3.f*m1*m1*m1*m1 + 6.f*m2*m1*m1 - 4.f*m3*m1 + m4;
            float kurt = m4c/(var*var) - 3.f;
            kurt = fminf(fmaxf(kurt, -3.f), 3.f);
            sum += kurt*kurt;
        }
    }
    red[t] = sum;
    __syncthreads();
    for (int off = 512; off > 0; off >>= 1) {
        if (t < off) red[t] += red[t+off];
        __syncthreads();
    }
    if (t == 0) {
        float na = 0.f;
        for (int c = 0; c < NCLS; ++c) na += (g_cntf[c] > 0.f) ? 1.f : 0.f;
        na = fmaxf(na, 1.f);
        out[0] = red[0] / ((float)DDIR * na);
    }
}

extern "C" void kernel_launch(void* const* d_in, const int* in_sizes, int n_in,
                              void* d_out, int out_size, void* d_ws, size_t ws_size,
                              hipStream_t stream) {
    const float* feat = (const float*)d_in[0];
    const int*   lab  = (const int*)d_in[1];
    const float* pm   = (const float*)d_in[2];
    float* out = (float*)d_out;

    const int eig_lds = (256 + TRI_N) * 4 + 64;   // producer needs the max

    (void)hipFuncSetAttribute((const void*)k_eigen,
        hipFuncAttributeMaxDynamicSharedMemorySize, eig_lds);

    hipLaunchKernelGGL(k_zero, dim3(3648), dim3(1024), 0, stream);
    hipLaunchKernelGGL(k_sums, dim3(256), dim3(256), 0, stream, feat, lab);
    hipLaunchKernelGGL(k_rank, dim3(NSEG), dim3(256), 0, stream, lab);
    hipLaunchKernelGGL(k_segscan, dim3(1), dim3(64), 0, stream);
    hipLaunchKernelGGL(k_scatter, dim3(32, 256), dim3(256), 0, stream, feat, lab);
    hipLaunchKernelGGL(k_covgemm, dim3(4, 4, NCLS), dim3(256), 0, stream);
    hipLaunchKernelGGL(k_eigen, dim3(NCLS + NCLS*4), dim3(1024), eig_lds, stream);
    hipLaunchKernelGGL(k_mgemm, dim3(4, 16, NCLS), dim3(256), 0, stream, pm);
    hipLaunchKernelGGL(k_fvmom, dim3(16, NCLS), dim3(256), 0, stream);
    hipLaunchKernelGGL(k_loss, dim3(1), dim3(1024), 0, stream, out);
}

// Round 3
// 6004.393 us; speedup vs baseline: 1.0074x; 1.0074x over previous
//
#include <hip/hip_runtime.h>
#include <math.h>

// Problem constants
#define NCLS 19
#define FDIM 256
#define DDIR 1024
#define NPIX 8192
#define KPAD 768            // per-class compacted-column padding (max n_c ~ 500)
#define NSWEEP 5
#define NROUND 255
#define NSTEP (NSWEEP*NROUND)
#define NPAIR 128
#define TRI_N 32896         // 256*257/2 packed element count (for init loop)
#define TRI_P 36864         // row-padded triangular size: rows padded to 32-dword multiples
#define NOFF 8128           // 128*127/2 off-diagonal group pairs (s1<s2)
#define NSEG 32             // 8192 / 256 label segments
#define VST 66              // replay V-state row stride (64 + 2 pad)
#define FLAGSTRIDE 16       // pad step-flags to 64B lines

// ---- device-global workspace ----
__device__ float g_cntf[NCLS];
__device__ float g_ns[NCLS];
__device__ float g_mu[NCLS][FDIM];
__device__ int   g_rank[NPIX];
__device__ int   g_segcnt[NSEG][NCLS];
__device__ int   g_segoff[NSEG][NCLS];
__device__ float g_X[NCLS][FDIM][KPAD];
__device__ float g_cov[NCLS][FDIM][FDIM];
__device__ unsigned long long g_rotlog[NCLS][NSTEP][NPAIR];  // packed (c,s)
__device__ int   g_step[NCLS*FLAGSTRIDE];
__device__ float g_eval[NCLS][FDIM];
__device__ float g_W[NCLS][FDIM][FDIM];
__device__ float g_M[NCLS][DDIR][FDIM];
__device__ float g_mom[NCLS][DDIR][4];

union PackCS { float2 f; unsigned long long u; };
union PackF  { float f; unsigned int u; };

// round-robin tournament pairing: 255 fixed, 0..254 rotate
__device__ __forceinline__ void get_pair(int r, int s, int& p, int& q) {
    int a, b;
    if (s == 0) { a = NROUND; b = r; }
    else {
        a = r + s; if (a >= NROUND) a -= NROUND;
        b = r - s; if (b < 0) b += NROUND;
    }
    p = min(a, b); q = max(a, b);
}

// Row-padded triangular addressing: every row padded to a 32-dword multiple,
// so every row base is 0 mod 32 and LDS bank = j mod 32 EXACTLY. All rotation
// accesses move j by +-1 per lane -> 64 lanes hit each bank exactly twice
// (2-way is free on CDNA4). This kills R1's periodic quadratic-stride
// conflicts structurally instead of randomizing them (R2's failed swizzle).
// rowbase(i) = 32*(B+1)*(16B + rr), B = i>>5, rr = i&31.
__device__ __forceinline__ int rowbase(int i) {
    int B = i >> 5, rr = i & 31;
    return ((B + 1) * ((B << 4) + rr)) << 5;
}
__device__ __forceinline__ int tadr(int i, int j) { return rowbase(i) + j; }   // i>=j
__device__ __forceinline__ int tadr2(int a, int b) {
    return a >= b ? tadr(a, b) : tadr(b, a);
}

// ---- K0: zero compacted buffer + flags + segment counters ----
__global__ __launch_bounds__(1024) void k_zero() {
    int idx = blockIdx.x*blockDim.x + threadIdx.x;
    const int total = NCLS*FDIM*KPAD;
    float* x = &g_X[0][0][0];
    for (int i = idx; i < total; i += gridDim.x*blockDim.x) x[i] = 0.f;
    if (idx < NCLS*FLAGSTRIDE) g_step[idx] = 0;
    if (idx < NSEG*NCLS) (&g_segcnt[0][0])[idx] = 0;
}

// ---- K1: per-class sums per feature + counts; writes mu/ns directly ----
__global__ void k_sums(const float* __restrict__ feat, const int* __restrict__ lab) {
    __shared__ float acc[NCLS][256];
    __shared__ float cnt[NCLS][256];
    int t = threadIdx.x;
    int f = blockIdx.x;
    for (int c = 0; c < NCLS; ++c) { acc[c][t] = 0.f; cnt[c][t] = 0.f; }
    for (int j = 0; j < NPIX/256; ++j) {
        int n = t + 256*j;
        int b = n >> 12, hw = n & 4095;
        float v = feat[(size_t)b*1048576 + (size_t)f*4096 + hw];
        int c = lab[n];
        acc[c][t] += v;
        cnt[c][t] += 1.f;
    }
    __syncthreads();
    for (int off = 128; off > 0; off >>= 1) {
        if (t < off)
            for (int c = 0; c < NCLS; ++c) {
                acc[c][t] += acc[c][t+off];
                cnt[c][t] += cnt[c][t+off];
            }
        __syncthreads();
    }
    if (t < NCLS) {
        float ns = fmaxf(cnt[t][0], 1.f);
        g_mu[t][f] = acc[t][0] / ns;      // identical operands/order as old musetup
        if (f == 0) { g_cntf[t] = cnt[t][0]; g_ns[t] = ns; }
    }
}

// ---- K3a: deterministic per-segment rank + per-segment class counts ----
__global__ void k_rank(const int* __restrict__ lab) {
    __shared__ int sl[256];
    int seg = blockIdx.x, t = threadIdx.x;
    int n = seg*256 + t;
    int c = lab[n];
    sl[t] = c;
    __syncthreads();
    int rnk = 0, tot = 0;
    for (int i = 0; i < 256; ++i) {
        int e = sl[i];
        if (e == c) { tot += 1; if (i < t) rnk += 1; }
    }
    g_rank[n] = rnk;
    if (rnk == 0) g_segcnt[seg][c] = tot;
}

// ---- K3b: exclusive scan of segment counts per class ----
__global__ void k_segscan() {
    int c = threadIdx.x;
    if (c < NCLS) {
        int run = 0;
        for (int s = 0; s < NSEG; ++s) {
            g_segoff[s][c] = run;
            run += g_segcnt[s][c];
        }
    }
}

// ---- K4: scatter centered features into per-class compacted matrix ----
__global__ void k_scatter(const float* __restrict__ feat, const int* __restrict__ lab) {
    int n = blockIdx.x*256 + threadIdx.x;
    int g = blockIdx.y;
    int c = lab[n];
    int pos = g_segoff[n >> 8][c] + g_rank[n];
    float v = feat[(size_t)(n>>12)*1048576 + (size_t)g*4096 + (n&4095)] - g_mu[c][g];
    g_X[c][g][pos] = v;
}

// ---- K5: cov = (Xc Xc^T)/ns ----
__global__ void k_covgemm() {
    int cls = blockIdx.z, ti = blockIdx.y, tj = blockIdx.x;
    __shared__ float At[64][17], Bt[64][17];
    int t = threadIdx.x, tx = t & 15, ty = t >> 4;
    float accv[4][4] = {};
    for (int k0 = 0; k0 < KPAD; k0 += 16) {
        #pragma unroll
        for (int l = 0; l < 4; ++l) {
            int idx = t*4 + l;
            int row = idx >> 4, col = idx & 15;
            At[row][col] = g_X[cls][ti*64+row][k0+col];
            Bt[row][col] = g_X[cls][tj*64+row][k0+col];
        }
        __syncthreads();
        #pragma unroll
        for (int kk = 0; kk < 16; ++kk) {
            float a[4], b[4];
            #pragma unroll
            for (int i = 0; i < 4; ++i) a[i] = At[ty*4+i][kk];
            #pragma unroll
            for (int j = 0; j < 4; ++j) b[j] = Bt[tx*4+j][kk];
            #pragma unroll
            for (int i = 0; i < 4; ++i)
                #pragma unroll
                for (int j = 0; j < 4; ++j) accv[i][j] += a[i]*b[j];
        }
        __syncthreads();
    }
    float invns = 1.f / g_ns[cls];
    #pragma unroll
    for (int i = 0; i < 4; ++i)
        #pragma unroll
        for (int j = 0; j < 4; ++j)
            g_cov[cls][ti*64+ty*4+i][tj*64+tx*4+j] = accv[i][j]*invns;
}

// ---- K6: FUSED eigensolver (producer = Jacobi, consumer = V accumulation
//          + fused eigen-sort / W write) ----
__global__ __launch_bounds__(1024) void k_eigen() {
    extern __shared__ float smem[];
    int t = threadIdx.x;

    if (blockIdx.x < NCLS) {
        // ================= Jacobi producer =================
        float2* pcs = (float2*)smem;  // 128 packed (c,s) -> 256-float footprint
        float* tri  = smem + 256;     // TRI_P floats (row-padded layout)
        int cls = blockIdx.x;

        for (int L = t; L < TRI_N; L += 1024) {
            int i = (int)((sqrtf(8.f*L+1.f)-1.f)*0.5f);
            while ((i+1)*(i+2)/2 <= L) ++i;
            while (i*(i+1)/2 > L) --i;
            int j = L - i*(i+1)/2;
            tri[tadr(i,j)] = g_cov[cls][i][j];
        }

        // Fixed-sA group mapping: thread rotates its own pair-index sA against
        // 8 partners sB = (sA + d) & 127 with d = 8k + h + 1 in 1..64.
        // Coverage: d=1..63 over all 128 origins covers each unordered group
        // once; d=64 (k==7,h==7) restricted to sA<64. Total = 8064+64 = 8128.
        // Skip pattern is wave-uniform (wave 15 skips k=7 entirely).
        const int sA = t & 127;
        const int h  = t >> 7;
        const bool k7ok = (h != 7) || (sA < 64);
        int sB[8];
        #pragma unroll
        for (int k = 0; k < 8; ++k) sB[k] = (sA + 8*k + h + 1) & 127;

        // Incremental round-robin state: for pair index s, a=(r+s)%255 (or 255
        // fixed when s==0), b=(r-s)%255; both advance +1 mod 255 per step.
        const bool zA = (sA == 0);
        int aA = zA ? NROUND : sA;
        int bA = zA ? 0 : NROUND - sA;
        int aB[8], bB[8];
        unsigned zBm = 0;
        #pragma unroll
        for (int k = 0; k < 8; ++k) {
            bool z = (sB[k] == 0);
            if (z) zBm |= 1u << k;
            aB[k] = z ? NROUND : sB[k];
            bB[k] = z ? 0 : NROUND - sB[k];
        }
        __syncthreads();

        for (int step = 0; step < NSTEP; ++step) {
            int r = step % NROUND;
            if (t < NPAIR) {
                int p, q; get_pair(r, t, p, q);
                float app = tri[tadr(p,p)], aqq = tri[tadr(q,q)];
                float apq = tri[tadr(q,p)];
                float c = 1.f, s = 0.f;
                if (fabsf(apq) > 1e-30f) {
                    float theta = (aqq - app) / (2.f*apq);
                    float tt = 1.f/(fabsf(theta) + sqrtf(theta*theta + 1.f));
                    if (theta < 0.f) tt = -tt;
                    c = 1.f/sqrtf(tt*tt + 1.f);
                    s = tt*c;
                }
                // store rotlog early: maximizes drain time before 2nd barrier
                PackCS pk; pk.f = make_float2(c, s);
                __hip_atomic_store(&g_rotlog[cls][step][t], pk.u,
                                   __ATOMIC_RELAXED, __HIP_MEMORY_SCOPE_AGENT);
                pcs[t] = make_float2(c, s);
                // diagonal 2x2 update (hazard-free: no off-diag group touches these)
                float napp = c*c*app - 2.f*c*s*apq + s*s*aqq;
                float naqq = s*s*app + 2.f*c*s*apq + c*c*aqq;
                tri[tadr(p,p)] = napp;
                tri[tadr(q,q)] = naqq;
                tri[tadr(q,p)] = 0.f;
            }
            __syncthreads();   // pcs + diag updates visible

            int pA = min(aA, bA), qA = max(aA, bA);
            float2 csA = pcs[sA];
            #pragma unroll
            for (int k = 0; k < 8; ++k) {
                if (k == 7 && !k7ok) continue;
                int pB = min(aB[k], bB[k]), qB = max(aB[k], bB[k]);
                float2 csB = pcs[sB[k]];
                // preserve original role order: smaller pair index acts on rows
                bool sw = sB[k] < sA;
                int p1 = sw ? pB : pA, q1 = sw ? qB : qA;
                int p2 = sw ? pA : pB, q2 = sw ? qA : qB;
                float c1 = sw ? csB.x : csA.x, sv1 = sw ? csB.y : csA.y;
                float c2 = sw ? csA.x : csB.x, sv2 = sw ? csA.y : csB.y;
                int i00 = tadr2(p1,p2), i01 = tadr2(p1,q2);
                int i10 = tadr2(q1,p2), i11 = tadr2(q1,q2);
                float B00 = tri[i00], B01 = tri[i01];
                float B10 = tri[i10], B11 = tri[i11];
                float X00 = c1*B00 - sv1*B10, X01 = c1*B01 - sv1*B11;
                float X10 = sv1*B00 + c1*B10, X11 = sv1*B01 + c1*B11;
                tri[i00] = c2*X00 - sv2*X01;
                tri[i01] = sv2*X00 + c2*X01;
                tri[i10] = c2*X10 - sv2*X11;
                tri[i11] = sv2*X10 + c2*X11;
            }
            // advance round-robin state (+1 mod 255; fixed slot stays at 255)
            bA = (bA+1 == NROUND) ? 0 : bA+1;
            if (!zA) aA = (aA+1 == NROUND) ? 0 : aA+1;
            #pragma unroll
            for (int k = 0; k < 8; ++k) {
                bB[k] = (bB[k]+1 == NROUND) ? 0 : bB[k]+1;
                if (!(zBm & (1u<<k))) aB[k] = (aB[k]+1 == NROUND) ? 0 : aB[k]+1;
            }
            __syncthreads();   // drains rotlog store (vmcnt0) + all LDS
            if (t == 0) {
                __hip_atomic_store(&g_step[cls*FLAGSTRIDE], step+1,
                                   __ATOMIC_RELAXED, __HIP_MEMORY_SCOPE_AGENT);
            }
        }
        // publish eigenvalues (agent-scope -> LLC) then release final flag
        for (int f = t; f < FDIM; f += 1024) {
            PackF pf; pf.f = tri[tadr(f,f)];
            __hip_atomic_store((unsigned int*)&g_eval[cls][f], pf.u,
                               __ATOMIC_RELAXED, __HIP_MEMORY_SCOPE_AGENT);
        }
        __syncthreads();       // drains eval stores
        if (t == 0) {
            __hip_atomic_store(&g_step[cls*FLAGSTRIDE], NSTEP+1,
                               __ATOMIC_RELAXED, __HIP_MEMORY_SCOPE_AGENT);
        }
    } else {
        // ======= eigenvector consumer (+ fused sort / W write) =======
        float2* lcs = (float2*)smem;            // 128 packed (c,s)
        float* st = smem + 256;                 // 256 x VST state (64 V-columns)
        float* evbuf = smem + 256 + 256*VST;    // 256 eigenvalues (reuse tail)
        int*   rkbuf = (int*)(evbuf + 256);     // 256 ranks
        int rb = blockIdx.x - NCLS;
        int cls = rb >> 2;
        int ibase = (rb & 3) * 64;

        for (int idx = t; idx < 256*64; idx += 1024) {
            int p = idx >> 6, col = idx & 63;
            st[p*VST + col] = (p == ibase + col) ? 1.f : 0.f;
        }

        int s0 = t >> 5;
        int cp = t & 31;
        // incremental pair state for s_w = s0 + 32w
        int aw[4], bw[4];
        unsigned zwm = 0;
        #pragma unroll
        for (int w = 0; w < 4; ++w) {
            int s = s0 + 32*w;
            bool z = (s == 0);
            if (z) zwm |= 1u << w;
            aw[w] = z ? NROUND : s;
            bw[w] = z ? 0 : NROUND - s;
        }
        __syncthreads();

        for (int step = 0; step < NSTEP; ++step) {
            if (t == 0) {
                while (__hip_atomic_load(&g_step[cls*FLAGSTRIDE], __ATOMIC_RELAXED,
                                         __HIP_MEMORY_SCOPE_AGENT) <= step)
                    __builtin_amdgcn_s_sleep(2);
            }
            __syncthreads();
            if (t < NPAIR) {
                PackCS pk;
                pk.u = __hip_atomic_load(&g_rotlog[cls][step][t],
                                         __ATOMIC_RELAXED, __HIP_MEMORY_SCOPE_AGENT);
                lcs[t] = pk.f;
            }
            __syncthreads();
            float2 xv[4], yv[4];
            float cv[4], sv[4];
            int pa[4], qa[4];
            #pragma unroll
            for (int w = 0; w < 4; ++w) {
                float2 cs = lcs[s0 + 32*w];
                cv[w] = cs.x; sv[w] = cs.y;
                pa[w] = min(aw[w], bw[w]); qa[w] = max(aw[w], bw[w]);
                xv[w] = *(float2*)&st[pa[w]*VST + 2*cp];
                yv[w] = *(float2*)&st[qa[w]*VST + 2*cp];
            }
            #pragma unroll
            for (int w = 0; w < 4; ++w) {
                float2 nx, ny;
                nx.x = cv[w]*xv[w].x - sv[w]*yv[w].x;
                nx.y = cv[w]*xv[w].y - sv[w]*yv[w].y;
                ny.x = sv[w]*xv[w].x + cv[w]*yv[w].x;
                ny.y = sv[w]*xv[w].y + cv[w]*yv[w].y;
                *(float2*)&st[pa[w]*VST + 2*cp] = nx;
                *(float2*)&st[qa[w]*VST + 2*cp] = ny;
            }
            #pragma unroll
            for (int w = 0; w < 4; ++w) {
                bw[w] = (bw[w]+1 == NROUND) ? 0 : bw[w]+1;
                if (!(zwm & (1u<<w))) aw[w] = (aw[w]+1 == NROUND) ? 0 : aw[w]+1;
            }
        }
        // wait for eigenvalues, rank them (identical comparator to old k_sort)
        if (t == 0) {
            while (__hip_atomic_load(&g_step[cls*FLAGSTRIDE], __ATOMIC_RELAXED,
                                     __HIP_MEMORY_SCOPE_AGENT) <= NSTEP)
                __builtin_amdgcn_s_sleep(2);
        }
        __syncthreads();
        if (t < 256) {
            PackF pf;
            pf.u = __hip_atomic_load((unsigned int*)&g_eval[cls][t],
                                     __ATOMIC_RELAXED, __HIP_MEMORY_SCOPE_AGENT);
            evbuf[t] = pf.f;
        }
        __syncthreads();
        if (t < 256) {
            float mine = evbuf[t];
            int r = 0;
            for (int f = 0; f < 256; ++f) {
                float o = evbuf[f];
                if (o > mine || (o == mine && f < t)) ++r;
            }
            rkbuf[t] = r;
        }
        __syncthreads();
        for (int idx = t; idx < 256*32; idx += 1024) {
            int f = idx >> 5, c2 = idx & 31;
            float2 v = *(float2*)&st[f*VST + 2*c2];
            *(float2*)&g_W[cls][rkbuf[f]][ibase + 2*c2] = v;
        }
    }
}

// ---- K10: M[c] = proj @ W[c]   (D x F) ----
__global__ void k_mgemm(const float* __restrict__ pm) {
    int cls = blockIdx.z, dt = blockIdx.y, gt = blockIdx.x;
    __shared__ float At[64][17], Bt[16][65];
    int t = threadIdx.x, tx = t & 15, ty = t >> 4;
    float accv[4][4] = {};
    for (int k0 = 0; k0 < FDIM; k0 += 16) {
        #pragma unroll
        for (int l = 0; l < 4; ++l) {
            int idx = t*4 + l;
            int row = idx >> 4, col = idx & 15;
            At[row][col] = pm[(size_t)(dt*64+row)*FDIM + k0 + col];
        }
        #pragma unroll
        for (int l = 0; l < 4; ++l) {
            int idx = t*4 + l;
            int row = idx >> 6, col = idx & 63;
            Bt[row][col] = g_W[cls][k0+row][gt*64+col];
        }
        __syncthreads();
        #pragma unroll
        for (int kk = 0; kk < 16; ++kk) {
            float a[4], b[4];
            #pragma unroll
            for (int i = 0; i < 4; ++i) a[i] = At[ty*4+i][kk];
            #pragma unroll
            for (int j = 0; j < 4; ++j) b[j] = Bt[kk][tx*4+j];
            #pragma unroll
            for (int i = 0; i < 4; ++i)
                #pragma unroll
                for (int j = 0; j < 4; ++j) accv[i][j] += a[i]*b[j];
        }
        __syncthreads();
    }
    #pragma unroll
    for (int i = 0; i < 4; ++i)
        #pragma unroll
        for (int j = 0; j < 4; ++j)
            g_M[cls][dt*64+ty*4+i][gt*64+tx*4+j] = accv[i][j];
}

// ---- K11: fv = M[c] @ Xc, accumulate moments m1..m4 over columns ----
__global__ void k_fvmom() {
    int cls = blockIdx.y, dt = blockIdx.x;
    __shared__ float Mt[64][17], Xt[16][65];
    __shared__ float red[64][16];
    int t = threadIdx.x, tx = t & 15, ty = t >> 4;
    float mm[4][4] = {};
    for (int kt = 0; kt < KPAD; kt += 64) {
        float accv[4][4] = {};
        for (int g0 = 0; g0 < FDIM; g0 += 16) {
            #pragma unroll
            for (int l = 0; l < 4; ++l) {
                int idx = t*4 + l;
                int row = idx >> 4, col = idx & 15;
                Mt[row][col] = g_M[cls][dt*64+row][g0+col];
            }
            #pragma unroll
            for (int l = 0; l < 4; ++l) {
                int idx = t*4 + l;
                int row = idx >> 6, col = idx & 63;
                Xt[row][col] = g_X[cls][g0+row][kt+col];
            }
            __syncthreads();
            #pragma unroll
            for (int kk = 0; kk < 16; ++kk) {
                float a[4], b[4];
                #pragma unroll
                for (int i = 0; i < 4; ++i) a[i] = Mt[ty*4+i][kk];
                #pragma unroll
                for (int j = 0; j < 4; ++j) b[j] = Xt[kk][tx*4+j];
                #pragma unroll
                for (int i = 0; i < 4; ++i)
                    #pragma unroll
                    for (int j = 0; j < 4; ++j) accv[i][j] += a[i]*b[j];
            }
            __syncthreads();
        }
        #pragma unroll
        for (int i = 0; i < 4; ++i)
            #pragma unroll
            for (int j = 0; j < 4; ++j) {
                float v = accv[i][j], v2 = v*v;
                mm[0][i] += v; mm[1][i] += v2; mm[2][i] += v2*v; mm[3][i] += v2*v2;
            }
    }
    #pragma unroll
    for (int m = 0; m < 4; ++m) {
        __syncthreads();
        #pragma unroll
        for (int i = 0; i < 4; ++i) red[ty*4+i][tx] = mm[m][i];
        __syncthreads();
        if (t < 64) {
            float s = 0.f;
            #pragma unroll
            for (int x = 0; x < 16; ++x) s += red[t][x];
            g_mom[cls][dt*64 + t][m] = s;
        }
    }
}

// ---- K12: kurtosis, clip, weighted mean -> loss ----
__global__ __launch_bounds__(1024) void k_loss(float* __restrict__ out) {
    __shared__ float red[1024];
    int t = threadIdx.x;
    float sum = 0.f;
    for (int id = t; id < NCLS*DDIR; id += 1024) {
        int c = id >> 10, d = id & 1023;
        float cntv = g_cntf[c];
        if (cntv > 0.f) {
            float invns = 1.f / g_ns[c];
            float m1 = g_mom[c][d][0]*invns;
            float m2 = g_mom[c][d][1]*invns;
            float m3 = g_mom[c][d][2]*invns;
            float m4 = g_mom[c][d][3]*invns;
            float var = fmaxf(m2 - m1*m1, 1e-16f);
            float m4c = -3.f*m1*m1*m1*m1 + 6.f*m2*m1*m1 - 4.f*m3*m1 + m4;
            float kurt = m4c/(var*var) - 3.f;
            kurt = fminf(fmaxf(kurt, -3.f), 3.f);
            sum += kurt*kurt;
        }
    }
    red[t] = sum;
    __syncthreads();
    for (int off = 512; off > 0; off >>= 1) {
        if (t < off) red[t] += red[t+off];
        __syncthreads();
    }
    if (t == 0) {
        float na = 0.f;
        for (int c = 0; c < NCLS; ++c) na += (g_cntf[c] > 0.f) ? 1.f : 0.f;
        na = fmaxf(na, 1.f);
        out[0] = red[0] / ((float)DDIR * na);
    }
}

extern "C" void kernel_launch(void* const* d_in, const int* in_sizes, int n_in,
                              void* d_out, int out_size, void* d_ws, size_t ws_size,
                              hipStream_t stream) {
    const float* feat = (const float*)d_in[0];
    const int*   lab  = (const int*)d_in[1];
    const float* pm   = (const float*)d_in[2];
    float* out = (float*)d_out;

    const int eig_lds = (256 + TRI_P) * 4 + 64;   // producer needs the max

    (void)hipFuncSetAttribute((const void*)k_eigen,
        hipFuncAttributeMaxDynamicSharedMemorySize, eig_lds);

    hipLaunchKernelGGL(k_zero, dim3(3648), dim3(1024), 0, stream);
    hipLaunchKernelGGL(k_sums, dim3(256), dim3(256), 0, stream, feat, lab);
    hipLaunchKernelGGL(k_rank, dim3(NSEG), dim3(256), 0, stream, lab);
    hipLaunchKernelGGL(k_segscan, dim3(1), dim3(64), 0, stream);
    hipLaunchKernelGGL(k_scatter, dim3(32, 256), dim3(256), 0, stream, feat, lab);
    hipLaunchKernelGGL(k_covgemm, dim3(4, 4, NCLS), dim3(256), 0, stream);
    hipLaunchKernelGGL(k_eigen, dim3(NCLS + NCLS*4), dim3(1024), eig_lds, stream);
    hipLaunchKernelGGL(k_mgemm, dim3(4, 16, NCLS), dim3(256), 0, stream, pm);
    hipLaunchKernelGGL(k_fvmom, dim3(16, NCLS), dim3(256), 0, stream);
    hipLaunchKernelGGL(k_loss, dim3(1), dim3(1024), 0, stream, out);
}

// Round 4
// 5961.873 us; speedup vs baseline: 1.0146x; 1.0071x over previous
//
#include <hip/hip_runtime.h>
#include <math.h>

// Problem constants
#define NCLS 19
#define FDIM 256
#define DDIR 1024
#define NPIX 8192
#define KPAD 768            // per-class compacted-column padding (max n_c ~ 500)
#define NSWEEP 5
#define NROUND 255
#define NSTEP (NSWEEP*NROUND)
#define NPAIR 128
#define TRI_N 32896         // 256*257/2 packed element count (for init loop)
#define TRI_P 36864         // row-padded triangular size: rows padded to 32-dword multiples
#define NOFF 8128           // 128*127/2 off-diagonal group pairs (s1<s2)
#define NSEG 32             // 8192 / 256 label segments
#define VST 66              // replay V-state row stride (64 + 2 pad)
#define FLAGSTRIDE 16       // pad step-flags to 64B lines

// ---- device-global workspace ----
__device__ float g_cntf[NCLS];
__device__ float g_ns[NCLS];
__device__ float g_mu[NCLS][FDIM];
__device__ int   g_rank[NPIX];
__device__ int   g_segcnt[NSEG][NCLS];
__device__ int   g_segoff[NSEG][NCLS];
__device__ float g_X[NCLS][FDIM][KPAD];
__device__ float g_cov[NCLS][FDIM][FDIM];
__device__ unsigned long long g_rotlog[NCLS][NSTEP][NPAIR];  // packed (c,s)
__device__ int   g_step[NCLS*FLAGSTRIDE];
__device__ float g_eval[NCLS][FDIM];
__device__ float g_W[NCLS][FDIM][FDIM];
__device__ float g_M[NCLS][DDIR][FDIM];
__device__ float g_mom[NCLS][DDIR][4];

union PackCS { float2 f; unsigned long long u; };
union PackF  { float f; unsigned int u; };

// round-robin tournament pairing: 255 fixed, 0..254 rotate
__device__ __forceinline__ void get_pair(int r, int s, int& p, int& q) {
    int a, b;
    if (s == 0) { a = NROUND; b = r; }
    else {
        a = r + s; if (a >= NROUND) a -= NROUND;
        b = r - s; if (b < 0) b += NROUND;
    }
    p = min(a, b); q = max(a, b);
}

// Row-padded triangular addressing: every row padded to a 32-dword multiple,
// so every row base is 0 mod 32 and LDS bank = j mod 32 exactly (kept from R3:
// lowest measured conflicts, 2.7e7). rowbase(i) = 32*(B+1)*(16B+rr).
__device__ __forceinline__ int rowbase(int i) {
    int B = i >> 5, rr = i & 31;
    return ((B + 1) * ((B << 4) + rr)) << 5;
}
__device__ __forceinline__ int tadr(int i, int j) { return rowbase(i) + j; }   // i>=j
__device__ __forceinline__ int tadr2(int a, int b) {
    return a >= b ? tadr(a, b) : tadr(b, a);
}

// ---- K0: zero compacted buffer + flags + segment counters ----
__global__ __launch_bounds__(1024) void k_zero() {
    int idx = blockIdx.x*blockDim.x + threadIdx.x;
    const int total = NCLS*FDIM*KPAD;
    float* x = &g_X[0][0][0];
    for (int i = idx; i < total; i += gridDim.x*blockDim.x) x[i] = 0.f;
    if (idx < NCLS*FLAGSTRIDE) g_step[idx] = 0;
    if (idx < NSEG*NCLS) (&g_segcnt[0][0])[idx] = 0;
}

// ---- K1: per-class sums per feature + counts; writes mu/ns directly ----
__global__ void k_sums(const float* __restrict__ feat, const int* __restrict__ lab) {
    __shared__ float acc[NCLS][256];
    __shared__ float cnt[NCLS][256];
    int t = threadIdx.x;
    int f = blockIdx.x;
    for (int c = 0; c < NCLS; ++c) { acc[c][t] = 0.f; cnt[c][t] = 0.f; }
    for (int j = 0; j < NPIX/256; ++j) {
        int n = t + 256*j;
        int b = n >> 12, hw = n & 4095;
        float v = feat[(size_t)b*1048576 + (size_t)f*4096 + hw];
        int c = lab[n];
        acc[c][t] += v;
        cnt[c][t] += 1.f;
    }
    __syncthreads();
    for (int off = 128; off > 0; off >>= 1) {
        if (t < off)
            for (int c = 0; c < NCLS; ++c) {
                acc[c][t] += acc[c][t+off];
                cnt[c][t] += cnt[c][t+off];
            }
        __syncthreads();
    }
    if (t < NCLS) {
        float ns = fmaxf(cnt[t][0], 1.f);
        g_mu[t][f] = acc[t][0] / ns;      // identical operands/order as old musetup
        if (f == 0) { g_cntf[t] = cnt[t][0]; g_ns[t] = ns; }
    }
}

// ---- K3a: deterministic per-segment rank + per-segment class counts ----
__global__ void k_rank(const int* __restrict__ lab) {
    __shared__ int sl[256];
    int seg = blockIdx.x, t = threadIdx.x;
    int n = seg*256 + t;
    int c = lab[n];
    sl[t] = c;
    __syncthreads();
    int rnk = 0, tot = 0;
    for (int i = 0; i < 256; ++i) {
        int e = sl[i];
        if (e == c) { tot += 1; if (i < t) rnk += 1; }
    }
    g_rank[n] = rnk;
    if (rnk == 0) g_segcnt[seg][c] = tot;
}

// ---- K3b: exclusive scan of segment counts per class ----
__global__ void k_segscan() {
    int c = threadIdx.x;
    if (c < NCLS) {
        int run = 0;
        for (int s = 0; s < NSEG; ++s) {
            g_segoff[s][c] = run;
            run += g_segcnt[s][c];
        }
    }
}

// ---- K4: scatter centered features into per-class compacted matrix ----
__global__ void k_scatter(const float* __restrict__ feat, const int* __restrict__ lab) {
    int n = blockIdx.x*256 + threadIdx.x;
    int g = blockIdx.y;
    int c = lab[n];
    int pos = g_segoff[n >> 8][c] + g_rank[n];
    float v = feat[(size_t)(n>>12)*1048576 + (size_t)g*4096 + (n&4095)] - g_mu[c][g];
    g_X[c][g][pos] = v;
}

// ---- K5: cov = (Xc Xc^T)/ns ----
__global__ void k_covgemm() {
    int cls = blockIdx.z, ti = blockIdx.y, tj = blockIdx.x;
    __shared__ float At[64][17], Bt[64][17];
    int t = threadIdx.x, tx = t & 15, ty = t >> 4;
    float accv[4][4] = {};
    for (int k0 = 0; k0 < KPAD; k0 += 16) {
        #pragma unroll
        for (int l = 0; l < 4; ++l) {
            int idx = t*4 + l;
            int row = idx >> 4, col = idx & 15;
            At[row][col] = g_X[cls][ti*64+row][k0+col];
            Bt[row][col] = g_X[cls][tj*64+row][k0+col];
        }
        __syncthreads();
        #pragma unroll
        for (int kk = 0; kk < 16; ++kk) {
            float a[4], b[4];
            #pragma unroll
            for (int i = 0; i < 4; ++i) a[i] = At[ty*4+i][kk];
            #pragma unroll
            for (int j = 0; j < 4; ++j) b[j] = Bt[tx*4+j][kk];
            #pragma unroll
            for (int i = 0; i < 4; ++i)
                #pragma unroll
                for (int j = 0; j < 4; ++j) accv[i][j] += a[i]*b[j];
        }
        __syncthreads();
    }
    float invns = 1.f / g_ns[cls];
    #pragma unroll
    for (int i = 0; i < 4; ++i)
        #pragma unroll
        for (int j = 0; j < 4; ++j)
            g_cov[cls][ti*64+ty*4+i][tj*64+tx*4+j] = accv[i][j]*invns;
}

// ---- K6: FUSED eigensolver (producer = Jacobi, consumer = V accumulation
//          + fused eigen-sort / W write) ----
__global__ __launch_bounds__(1024, 4) void k_eigen() {
    extern __shared__ float smem[];
    int t = threadIdx.x;

    if (blockIdx.x < NCLS) {
        // ================= Jacobi producer =================
        float2* pcs = (float2*)smem;  // 128 packed (c,s) -> 256-float footprint
        float* tri  = smem + 256;     // TRI_P floats (row-padded layout)
        int cls = blockIdx.x;

        for (int L = t; L < TRI_N; L += 1024) {
            int i = (int)((sqrtf(8.f*L+1.f)-1.f)*0.5f);
            while ((i+1)*(i+2)/2 <= L) ++i;
            while (i*(i+1)/2 > L) --i;
            int j = L - i*(i+1)/2;
            tri[tadr(i,j)] = g_cov[cls][i][j];
        }

        // Fixed-sA group mapping: thread rotates its own pair-index sA against
        // 8 partners sB = (sA + d) & 127 with d = 8k + h + 1 in 1..64.
        // Coverage: d=1..63 over all 128 origins covers each unordered group
        // once; d=64 (k==7,h==7) restricted to sA<64. Total = 8064+64 = 8128.
        // Skip pattern is wave-uniform (wave 15 skips k=7 entirely).
        const int sA = t & 127;
        const int h  = t >> 7;
        const bool k7ok = (h != 7) || (sA < 64);
        int sB[8];
        #pragma unroll
        for (int k = 0; k < 8; ++k) sB[k] = (sA + 8*k + h + 1) & 127;

        // Incremental round-robin state: for pair index s, a=(r+s)%255 (or 255
        // fixed when s==0), b=(r-s)%255; both advance +1 mod 255 per step.
        const bool zA = (sA == 0);
        int aA = zA ? NROUND : sA;
        int bA = zA ? 0 : NROUND - sA;
        int aB[8], bB[8];
        unsigned zBm = 0;
        #pragma unroll
        for (int k = 0; k < 8; ++k) {
            bool z = (sB[k] == 0);
            if (z) zBm |= 1u << k;
            aB[k] = z ? NROUND : sB[k];
            bB[k] = z ? 0 : NROUND - sB[k];
        }
        __syncthreads();

        for (int step = 0; step < NSTEP; ++step) {
            int r = step % NROUND;
            if (t < NPAIR) {
                int p, q; get_pair(r, t, p, q);
                float app = tri[tadr(p,p)], aqq = tri[tadr(q,q)];
                float apq = tri[tadr(q,p)];
                float c = 1.f, s = 0.f;
                if (fabsf(apq) > 1e-30f) {
                    float theta = (aqq - app) / (2.f*apq);
                    float tt = 1.f/(fabsf(theta) + sqrtf(theta*theta + 1.f));
                    if (theta < 0.f) tt = -tt;
                    c = 1.f/sqrtf(tt*tt + 1.f);
                    s = tt*c;
                }
                // store rotlog early: maximizes drain time before 2nd barrier
                PackCS pk; pk.f = make_float2(c, s);
                __hip_atomic_store(&g_rotlog[cls][step][t], pk.u,
                                   __ATOMIC_RELAXED, __HIP_MEMORY_SCOPE_AGENT);
                pcs[t] = make_float2(c, s);
                // diagonal 2x2 update (hazard-free: no off-diag group touches these)
                float napp = c*c*app - 2.f*c*s*apq + s*s*aqq;
                float naqq = s*s*app + 2.f*c*s*apq + c*c*aqq;
                tri[tadr(p,p)] = napp;
                tri[tadr(q,q)] = naqq;
                tri[tadr(q,p)] = 0.f;
            }
            __syncthreads();   // pcs + diag updates visible

            // Off-diagonal phase, latency-batched: two batches of 4 groups.
            // All addresses + 16 ds_reads issued per batch into statically
            // indexed register arrays (rule #20: full unroll), one wait, then
            // FMAs + 16 writes. Collapses 8 exposed LDS latencies to 2.
            // Inter-thread safe: each unordered group {sA,sB} is owned by
            // exactly one thread; elements disjoint from the diag set.
            int pA = min(aA, bA), qA = max(aA, bA);
            float2 csA = pcs[sA];
            #pragma unroll
            for (int half = 0; half < 2; ++half) {
                int   adr[4][4];
                float Bv[4][4];
                float c1a[4], s1a[4], c2a[4], s2a[4];
                #pragma unroll
                for (int kk = 0; kk < 4; ++kk) {
                    const int k = half*4 + kk;
                    int pB = min(aB[k], bB[k]), qB = max(aB[k], bB[k]);
                    float2 csB = pcs[sB[k]];
                    // preserve original role order: smaller pair index on rows
                    bool sw = sB[k] < sA;
                    int p1 = sw ? pB : pA, q1 = sw ? qB : qA;
                    int p2 = sw ? pA : pB, q2 = sw ? qA : qB;
                    c1a[kk] = sw ? csB.x : csA.x; s1a[kk] = sw ? csB.y : csA.y;
                    c2a[kk] = sw ? csA.x : csB.x; s2a[kk] = sw ? csA.y : csB.y;
                    adr[kk][0] = tadr2(p1,p2); adr[kk][1] = tadr2(p1,q2);
                    adr[kk][2] = tadr2(q1,p2); adr[kk][3] = tadr2(q1,q2);
                    if (!(k == 7 && !k7ok)) {
                        Bv[kk][0] = tri[adr[kk][0]];
                        Bv[kk][1] = tri[adr[kk][1]];
                        Bv[kk][2] = tri[adr[kk][2]];
                        Bv[kk][3] = tri[adr[kk][3]];
                    }
                }
                #pragma unroll
                for (int kk = 0; kk < 4; ++kk) {
                    const int k = half*4 + kk;
                    if (k == 7 && !k7ok) continue;
                    float c1 = c1a[kk], sv1 = s1a[kk];
                    float c2 = c2a[kk], sv2 = s2a[kk];
                    float B00 = Bv[kk][0], B01 = Bv[kk][1];
                    float B10 = Bv[kk][2], B11 = Bv[kk][3];
                    float X00 = c1*B00 - sv1*B10, X01 = c1*B01 - sv1*B11;
                    float X10 = sv1*B00 + c1*B10, X11 = sv1*B01 + c1*B11;
                    tri[adr[kk][0]] = c2*X00 - sv2*X01;
                    tri[adr[kk][1]] = sv2*X00 + c2*X01;
                    tri[adr[kk][2]] = c2*X10 - sv2*X11;
                    tri[adr[kk][3]] = sv2*X10 + c2*X11;
                }
            }
            // advance round-robin state (+1 mod 255; fixed slot stays at 255)
            bA = (bA+1 == NROUND) ? 0 : bA+1;
            if (!zA) aA = (aA+1 == NROUND) ? 0 : aA+1;
            #pragma unroll
            for (int k = 0; k < 8; ++k) {
                bB[k] = (bB[k]+1 == NROUND) ? 0 : bB[k]+1;
                if (!(zBm & (1u<<k))) aB[k] = (aB[k]+1 == NROUND) ? 0 : aB[k]+1;
            }
            __syncthreads();   // drains rotlog store (vmcnt0) + all LDS
            if (t == 0) {
                __hip_atomic_store(&g_step[cls*FLAGSTRIDE], step+1,
                                   __ATOMIC_RELAXED, __HIP_MEMORY_SCOPE_AGENT);
            }
        }
        // publish eigenvalues (agent-scope -> LLC) then release final flag
        for (int f = t; f < FDIM; f += 1024) {
            PackF pf; pf.f = tri[tadr(f,f)];
            __hip_atomic_store((unsigned int*)&g_eval[cls][f], pf.u,
                               __ATOMIC_RELAXED, __HIP_MEMORY_SCOPE_AGENT);
        }
        __syncthreads();       // drains eval stores
        if (t == 0) {
            __hip_atomic_store(&g_step[cls*FLAGSTRIDE], NSTEP+1,
                               __ATOMIC_RELAXED, __HIP_MEMORY_SCOPE_AGENT);
        }
    } else {
        // ======= eigenvector consumer (+ fused sort / W write) =======
        float2* lcs = (float2*)smem;            // 128 packed (c,s)
        float* st = smem + 256;                 // 256 x VST state (64 V-columns)
        float* evbuf = smem + 256 + 256*VST;    // 256 eigenvalues (reuse tail)
        int*   rkbuf = (int*)(evbuf + 256);     // 256 ranks
        int rb = blockIdx.x - NCLS;
        int cls = rb >> 2;
        int ibase = (rb & 3) * 64;

        for (int idx = t; idx < 256*64; idx += 1024) {
            int p = idx >> 6, col = idx & 63;
            st[p*VST + col] = (p == ibase + col) ? 1.f : 0.f;
        }

        int s0 = t >> 5;
        int cp = t & 31;
        // incremental pair state for s_w = s0 + 32w
        int aw[4], bw[4];
        unsigned zwm = 0;
        #pragma unroll
        for (int w = 0; w < 4; ++w) {
            int s = s0 + 32*w;
            bool z = (s == 0);
            if (z) zwm |= 1u << w;
            aw[w] = z ? NROUND : s;
            bw[w] = z ? 0 : NROUND - s;
        }
        __syncthreads();

        for (int step = 0; step < NSTEP; ++step) {
            if (t == 0) {
                while (__hip_atomic_load(&g_step[cls*FLAGSTRIDE], __ATOMIC_RELAXED,
                                         __HIP_MEMORY_SCOPE_AGENT) <= step)
                    __builtin_amdgcn_s_sleep(2);
            }
            __syncthreads();
            if (t < NPAIR) {
                PackCS pk;
                pk.u = __hip_atomic_load(&g_rotlog[cls][step][t],
                                         __ATOMIC_RELAXED, __HIP_MEMORY_SCOPE_AGENT);
                lcs[t] = pk.f;
            }
            __syncthreads();
            float2 xv[4], yv[4];
            float cv[4], sv[4];
            int pa[4], qa[4];
            #pragma unroll
            for (int w = 0; w < 4; ++w) {
                float2 cs = lcs[s0 + 32*w];
                cv[w] = cs.x; sv[w] = cs.y;
                pa[w] = min(aw[w], bw[w]); qa[w] = max(aw[w], bw[w]);
                xv[w] = *(float2*)&st[pa[w]*VST + 2*cp];
                yv[w] = *(float2*)&st[qa[w]*VST + 2*cp];
            }
            #pragma unroll
            for (int w = 0; w < 4; ++w) {
                float2 nx, ny;
                nx.x = cv[w]*xv[w].x - sv[w]*yv[w].x;
                nx.y = cv[w]*xv[w].y - sv[w]*yv[w].y;
                ny.x = sv[w]*xv[w].x + cv[w]*yv[w].x;
                ny.y = sv[w]*xv[w].y + cv[w]*yv[w].y;
                *(float2*)&st[pa[w]*VST + 2*cp] = nx;
                *(float2*)&st[qa[w]*VST + 2*cp] = ny;
            }
            #pragma unroll
            for (int w = 0; w < 4; ++w) {
                bw[w] = (bw[w]+1 == NROUND) ? 0 : bw[w]+1;
                if (!(zwm & (1u<<w))) aw[w] = (aw[w]+1 == NROUND) ? 0 : aw[w]+1;
            }
        }
        // wait for eigenvalues, rank them (identical comparator to old k_sort)
        if (t == 0) {
            while (__hip_atomic_load(&g_step[cls*FLAGSTRIDE], __ATOMIC_RELAXED,
                                     __HIP_MEMORY_SCOPE_AGENT) <= NSTEP)
                __builtin_amdgcn_s_sleep(2);
        }
        __syncthreads();
        if (t < 256) {
            PackF pf;
            pf.u = __hip_atomic_load((unsigned int*)&g_eval[cls][t],
                                     __ATOMIC_RELAXED, __HIP_MEMORY_SCOPE_AGENT);
            evbuf[t] = pf.f;
        }
        __syncthreads();
        if (t < 256) {
            float mine = evbuf[t];
            int r = 0;
            for (int f = 0; f < 256; ++f) {
                float o = evbuf[f];
                if (o > mine || (o == mine && f < t)) ++r;
            }
            rkbuf[t] = r;
        }
        __syncthreads();
        for (int idx = t; idx < 256*32; idx += 1024) {
            int f = idx >> 5, c2 = idx & 31;
            float2 v = *(float2*)&st[f*VST + 2*c2];
            *(float2*)&g_W[cls][rkbuf[f]][ibase + 2*c2] = v;
        }
    }
}

// ---- K10: M[c] = proj @ W[c]   (D x F) ----
__global__ void k_mgemm(const float* __restrict__ pm) {
    int cls = blockIdx.z, dt = blockIdx.y, gt = blockIdx.x;
    __shared__ float At[64][17], Bt[16][65];
    int t = threadIdx.x, tx = t & 15, ty = t >> 4;
    float accv[4][4] = {};
    for (int k0 = 0; k0 < FDIM; k0 += 16) {
        #pragma unroll
        for (int l = 0; l < 4; ++l) {
            int idx = t*4 + l;
            int row = idx >> 4, col = idx & 15;
            At[row][col] = pm[(size_t)(dt*64+row)*FDIM + k0 + col];
        }
        #pragma unroll
        for (int l = 0; l < 4; ++l) {
            int idx = t*4 + l;
            int row = idx >> 6, col = idx & 63;
            Bt[row][col] = g_W[cls][k0+row][gt*64+col];
        }
        __syncthreads();
        #pragma unroll
        for (int kk = 0; kk < 16; ++kk) {
            float a[4], b[4];
            #pragma unroll
            for (int i = 0; i < 4; ++i) a[i] = At[ty*4+i][kk];
            #pragma unroll
            for (int j = 0; j < 4; ++j) b[j] = Bt[kk][tx*4+j];
            #pragma unroll
            for (int i = 0; i < 4; ++i)
                #pragma unroll
                for (int j = 0; j < 4; ++j) accv[i][j] += a[i]*b[j];
        }
        __syncthreads();
    }
    #pragma unroll
    for (int i = 0; i < 4; ++i)
        #pragma unroll
        for (int j = 0; j < 4; ++j)
            g_M[cls][dt*64+ty*4+i][gt*64+tx*4+j] = accv[i][j];
}

// ---- K11: fv = M[c] @ Xc, accumulate moments m1..m4 over columns ----
__global__ void k_fvmom() {
    int cls = blockIdx.y, dt = blockIdx.x;
    __shared__ float Mt[64][17], Xt[16][65];
    __shared__ float red[64][16];
    int t = threadIdx.x, tx = t & 15, ty = t >> 4;
    float mm[4][4] = {};
    for (int kt = 0; kt < KPAD; kt += 64) {
        float accv[4][4] = {};
        for (int g0 = 0; g0 < FDIM; g0 += 16) {
            #pragma unroll
            for (int l = 0; l < 4; ++l) {
                int idx = t*4 + l;
                int row = idx >> 4, col = idx & 15;
                Mt[row][col] = g_M[cls][dt*64+row][g0+col];
            }
            #pragma unroll
            for (int l = 0; l < 4; ++l) {
                int idx = t*4 + l;
                int row = idx >> 6, col = idx & 63;
                Xt[row][col] = g_X[cls][g0+row][kt+col];
            }
            __syncthreads();
            #pragma unroll
            for (int kk = 0; kk < 16; ++kk) {
                float a[4], b[4];
                #pragma unroll
                for (int i = 0; i < 4; ++i) a[i] = Mt[ty*4+i][kk];
                #pragma unroll
                for (int j = 0; j < 4; ++j) b[j] = Xt[kk][tx*4+j];
                #pragma unroll
                for (int i = 0; i < 4; ++i)
                    #pragma unroll
                    for (int j = 0; j < 4; ++j) accv[i][j] += a[i]*b[j];
            }
            __syncthreads();
        }
        #pragma unroll
        for (int i = 0; i < 4; ++i)
            #pragma unroll
            for (int j = 0; j < 4; ++j) {
                float v = accv[i][j], v2 = v*v;
                mm[0][i] += v; mm[1][i] += v2; mm[2][i] += v2*v; mm[3][i] += v2*v2;
            }
    }
    #pragma unroll
    for (int m = 0; m < 4; ++m) {
        __syncthreads();
        #pragma unroll
        for (int i = 0; i < 4; ++i) red[ty*4+i][tx] = mm[m][i];
        __syncthreads();
        if (t < 64) {
            float s = 0.f;
            #pragma unroll
            for (int x = 0; x < 16; ++x) s += red[t][x];
            g_mom[cls][dt*64 + t][m] = s;
        }
    }
}

// ---- K12: kurtosis, clip, weighted mean -> loss ----
__global__ __launch_bounds__(1024) void k_loss(float* __restrict__ out) {
    __shared__ float red[1024];
    int t = threadIdx.x;
    float sum = 0.f;
    for (int id = t; id < NCLS*DDIR; id += 1024) {
        int c = id >> 10, d = id & 1023;
        float cntv = g_cntf[c];
        if (cntv > 0.f) {
            float invns = 1.f / g_ns[c];
            float m1 = g_mom[c][d][0]*invns;
            float m2 = g_mom[c][d][1]*invns;
            float m3 = g_mom[c][d][2]*invns;
            float m4 = g_mom[c][d][3]*invns;
            float var = fmaxf(m2 - m1*m1, 1e-16f);
            float m4c = -3.f*m1*m1*m1*m1 + 6.f*m2*m1*m1 - 4.f*m3*m1 + m4;
            float kurt = m4c/(var*var) - 3.f;
            kurt = fminf(fmaxf(kurt, -3.f), 3.f);
            sum += kurt*kurt;
        }
    }
    red[t] = sum;
    __syncthreads();
    for (int off = 512; off > 0; off >>= 1) {
        if (t < off) red[t] += red[t+off];
        __syncthreads();
    }
    if (t == 0) {
        float na = 0.f;
        for (int c = 0; c < NCLS; ++c) na += (g_cntf[c] > 0.f) ? 1.f : 0.f;
        na = fmaxf(na, 1.f);
        out[0] = red[0] / ((float)DDIR * na);
    }
}

extern "C" void kernel_launch(void* const* d_in, const int* in_sizes, int n_in,
                              void* d_out, int out_size, void* d_ws, size_t ws_size,
                              hipStream_t stream) {
    const float* feat = (const float*)d_in[0];
    const int*   lab  = (const int*)d_in[1];
    const float* pm   = (const float*)d_in[2];
    float* out = (float*)d_out;

    const int eig_lds = (256 + TRI_P) * 4 + 64;   // producer needs the max

    (void)hipFuncSetAttribute((const void*)k_eigen,
        hipFuncAttributeMaxDynamicSharedMemorySize, eig_lds);

    hipLaunchKernelGGL(k_zero, dim3(3648), dim3(1024), 0, stream);
    hipLaunchKernelGGL(k_sums, dim3(256), dim3(256), 0, stream, feat, lab);
    hipLaunchKernelGGL(k_rank, dim3(NSEG), dim3(256), 0, stream, lab);
    hipLaunchKernelGGL(k_segscan, dim3(1), dim3(64), 0, stream);
    hipLaunchKernelGGL(k_scatter, dim3(32, 256), dim3(256), 0, stream, feat, lab);
    hipLaunchKernelGGL(k_covgemm, dim3(4, 4, NCLS), dim3(256), 0, stream);
    hipLaunchKernelGGL(k_eigen, dim3(NCLS + NCLS*4), dim3(1024), eig_lds, stream);
    hipLaunchKernelGGL(k_mgemm, dim3(4, 16, NCLS), dim3(256), 0, stream, pm);
    hipLaunchKernelGGL(k_fvmom, dim3(16, NCLS), dim3(256), 0, stream);
    hipLaunchKernelGGL(k_loss, dim3(1), dim3(1024), 0, stream, out);
}

// Round 5
// 5768.414 us; speedup vs baseline: 1.0486x; 1.0335x over previous
//
#include <hip/hip_runtime.h>
#include <math.h>

// Problem constants
#define NCLS 19
#define FDIM 256
#define DDIR 1024
#define NPIX 8192
#define KPAD 768            // per-class compacted-column padding (max n_c ~ 500)
#define NSWEEP 5
#define NROUND 255
#define NSTEP (NSWEEP*NROUND)
#define NPAIR 128
#define TRI_N 32896         // 256*257/2 packed triangular size
#define NOFF 8128           // 128*127/2 off-diagonal group pairs (s1<s2)
#define NSEG 32             // 8192 / 256 label segments
#define VST 66              // replay V-state row stride (64 + 2 pad)
#define FLAGSTRIDE 16       // pad step-flags to 64B lines

// ---- device-global workspace ----
__device__ float g_cntf[NCLS];
__device__ float g_ns[NCLS];
__device__ float g_mu[NCLS][FDIM];
__device__ int   g_rank[NPIX];
__device__ int   g_segcnt[NSEG][NCLS];
__device__ int   g_segoff[NSEG][NCLS];
__device__ float g_X[NCLS][FDIM][KPAD];
__device__ float g_cov[NCLS][FDIM][FDIM];
__device__ unsigned long long g_rotlog[NCLS][NSTEP][NPAIR];  // packed (c,s)
__device__ int   g_step[NCLS*FLAGSTRIDE];
__device__ float g_eval[NCLS][FDIM];
__device__ float g_W[NCLS][FDIM][FDIM];
__device__ float g_M[NCLS][DDIR][FDIM];
__device__ float g_mom[NCLS][DDIR][4];

union PackCS { float2 f; unsigned long long u; };
union PackF  { float f; unsigned int u; };

// round-robin tournament pairing: 255 fixed, 0..254 rotate
__device__ __forceinline__ void get_pair(int r, int s, int& p, int& q) {
    int a, b;
    if (s == 0) { a = NROUND; b = r; }
    else {
        a = r + s; if (a >= NROUND) a -= NROUND;
        b = r - s; if (b < 0) b += NROUND;
    }
    p = min(a, b); q = max(a, b);
}

// Packed triangular addressing (R1 layout — empirically fastest; R2 swizzle
// and R3 row-padding both regressed 1.2ms regardless of conflict count).
__device__ __forceinline__ int tidx(int i, int j) { return ((i*(i+1))>>1) + j; } // i>=j
__device__ __forceinline__ int tidx2(int a, int b) { return a >= b ? tidx(a,b) : tidx(b,a); }

// ---- K0: zero compacted buffer + flags + segment counters ----
__global__ __launch_bounds__(1024) void k_zero() {
    int idx = blockIdx.x*blockDim.x + threadIdx.x;
    const int total = NCLS*FDIM*KPAD;
    float* x = &g_X[0][0][0];
    for (int i = idx; i < total; i += gridDim.x*blockDim.x) x[i] = 0.f;
    if (idx < NCLS*FLAGSTRIDE) g_step[idx] = 0;
    if (idx < NSEG*NCLS) (&g_segcnt[0][0])[idx] = 0;
}

// ---- K1: per-class sums per feature + counts; writes mu/ns directly ----
__global__ void k_sums(const float* __restrict__ feat, const int* __restrict__ lab) {
    __shared__ float acc[NCLS][256];
    __shared__ float cnt[NCLS][256];
    int t = threadIdx.x;
    int f = blockIdx.x;
    for (int c = 0; c < NCLS; ++c) { acc[c][t] = 0.f; cnt[c][t] = 0.f; }
    for (int j = 0; j < NPIX/256; ++j) {
        int n = t + 256*j;
        int b = n >> 12, hw = n & 4095;
        float v = feat[(size_t)b*1048576 + (size_t)f*4096 + hw];
        int c = lab[n];
        acc[c][t] += v;
        cnt[c][t] += 1.f;
    }
    __syncthreads();
    for (int off = 128; off > 0; off >>= 1) {
        if (t < off)
            for (int c = 0; c < NCLS; ++c) {
                acc[c][t] += acc[c][t+off];
                cnt[c][t] += cnt[c][t+off];
            }
        __syncthreads();
    }
    if (t < NCLS) {
        float ns = fmaxf(cnt[t][0], 1.f);
        g_mu[t][f] = acc[t][0] / ns;      // identical operands/order as old musetup
        if (f == 0) { g_cntf[t] = cnt[t][0]; g_ns[t] = ns; }
    }
}

// ---- K3a: deterministic per-segment rank + per-segment class counts ----
__global__ void k_rank(const int* __restrict__ lab) {
    __shared__ int sl[256];
    int seg = blockIdx.x, t = threadIdx.x;
    int n = seg*256 + t;
    int c = lab[n];
    sl[t] = c;
    __syncthreads();
    int rnk = 0, tot = 0;
    for (int i = 0; i < 256; ++i) {
        int e = sl[i];
        if (e == c) { tot += 1; if (i < t) rnk += 1; }
    }
    g_rank[n] = rnk;
    if (rnk == 0) g_segcnt[seg][c] = tot;
}

// ---- K3b: exclusive scan of segment counts per class ----
__global__ void k_segscan() {
    int c = threadIdx.x;
    if (c < NCLS) {
        int run = 0;
        for (int s = 0; s < NSEG; ++s) {
            g_segoff[s][c] = run;
            run += g_segcnt[s][c];
        }
    }
}

// ---- K4: scatter centered features into per-class compacted matrix ----
__global__ void k_scatter(const float* __restrict__ feat, const int* __restrict__ lab) {
    int n = blockIdx.x*256 + threadIdx.x;
    int g = blockIdx.y;
    int c = lab[n];
    int pos = g_segoff[n >> 8][c] + g_rank[n];
    float v = feat[(size_t)(n>>12)*1048576 + (size_t)g*4096 + (n&4095)] - g_mu[c][g];
    g_X[c][g][pos] = v;
}

// ---- K5: cov = (Xc Xc^T)/ns ----
__global__ void k_covgemm() {
    int cls = blockIdx.z, ti = blockIdx.y, tj = blockIdx.x;
    __shared__ float At[64][17], Bt[64][17];
    int t = threadIdx.x, tx = t & 15, ty = t >> 4;
    float accv[4][4] = {};
    for (int k0 = 0; k0 < KPAD; k0 += 16) {
        #pragma unroll
        for (int l = 0; l < 4; ++l) {
            int idx = t*4 + l;
            int row = idx >> 4, col = idx & 15;
            At[row][col] = g_X[cls][ti*64+row][k0+col];
            Bt[row][col] = g_X[cls][tj*64+row][k0+col];
        }
        __syncthreads();
        #pragma unroll
        for (int kk = 0; kk < 16; ++kk) {
            float a[4], b[4];
            #pragma unroll
            for (int i = 0; i < 4; ++i) a[i] = At[ty*4+i][kk];
            #pragma unroll
            for (int j = 0; j < 4; ++j) b[j] = Bt[tx*4+j][kk];
            #pragma unroll
            for (int i = 0; i < 4; ++i)
                #pragma unroll
                for (int j = 0; j < 4; ++j) accv[i][j] += a[i]*b[j];
        }
        __syncthreads();
    }
    float invns = 1.f / g_ns[cls];
    #pragma unroll
    for (int i = 0; i < 4; ++i)
        #pragma unroll
        for (int j = 0; j < 4; ++j)
            g_cov[cls][ti*64+ty*4+i][tj*64+tx*4+j] = accv[i][j]*invns;
}

// ---- K6: FUSED eigensolver (producer = Jacobi, consumer = V accumulation
//          + fused eigen-sort / W write) ----
__global__ __launch_bounds__(1024, 4) void k_eigen() {
    extern __shared__ float smem[];
    int t = threadIdx.x;

    if (blockIdx.x < NCLS) {
        // ================= Jacobi producer =================
        float2* pcs = (float2*)smem;  // 128 packed (c,s) -> 256-float footprint
        float* tri  = smem + 256;     // TRI_N floats (packed layout)
        int cls = blockIdx.x;

        for (int L = t; L < TRI_N; L += 1024) {
            int i = (int)((sqrtf(8.f*L+1.f)-1.f)*0.5f);
            while ((i+1)*(i+2)/2 <= L) ++i;
            while (i*(i+1)/2 > L) --i;
            int j = L - i*(i+1)/2;
            tri[L] = g_cov[cls][i][j];
        }

        // Fixed-sA group mapping: thread rotates its own pair-index sA against
        // 8 partners sB = (sA + d) & 127 with d = 8k + h + 1 in 1..64.
        // Coverage: d=1..63 over all 128 origins covers each unordered group
        // once; d=64 (k==7,h==7) restricted to sA<64. Total = 8064+64 = 8128.
        // Skip pattern is wave-uniform (wave 15 skips k=7 entirely).
        const int sA = t & 127;
        const int h  = t >> 7;
        const bool k7ok = (h != 7) || (sA < 64);
        int sB[8];
        #pragma unroll
        for (int k = 0; k < 8; ++k) sB[k] = (sA + 8*k + h + 1) & 127;

        // Incremental round-robin state: for pair index s, a=(r+s)%255 (or 255
        // fixed when s==0), b=(r-s)%255; both advance +1 mod 255 per step.
        const bool zA = (sA == 0);
        int aA = zA ? NROUND : sA;
        int bA = zA ? 0 : NROUND - sA;
        int aB[8], bB[8];
        unsigned zBm = 0;
        #pragma unroll
        for (int k = 0; k < 8; ++k) {
            bool z = (sB[k] == 0);
            if (z) zBm |= 1u << k;
            aB[k] = z ? NROUND : sB[k];
            bB[k] = z ? 0 : NROUND - sB[k];
        }
        __syncthreads();

        for (int step = 0; step < NSTEP; ++step) {
            // current pair for sA (for t<128, sA==t -> this IS the diag pair)
            int pA = min(aA, bA), qA = max(aA, bA);

            // ---- diag reads first (oldest outstanding -> ready earliest) ----
            float app = 0.f, aqq = 0.f, apq = 0.f;
            if (t < NPAIR) {
                app = tri[tidx(pA,pA)];
                aqq = tri[tidx(qA,qA)];
                apq = tri[tidx(qA,pA)];
            }

            // ---- pre-issue ALL 32 off-diag reads BEFORE the diag barrier ----
            // Safe: off-diag 2x2 blocks mix two different pairs, diag writes
            // touch elements with both coords in one pair -> disjoint. Reads
            // vs prev-step writes are ordered by the step-end barrier. The
            // post-diag __syncthreads drains lgkmcnt, acting as the wait.
            // Their pipe time executes in the diag phase's LDS-idle shadow.
            int adr0[8], adr1[8], adr2[8], adr3[8];
            float Bv0[8], Bv1[8], Bv2[8], Bv3[8];
            #pragma unroll
            for (int k = 0; k < 8; ++k) {
                int pB = min(aB[k], bB[k]), qB = max(aB[k], bB[k]);
                // preserve original role order: smaller pair index acts on rows
                bool sw = sB[k] < sA;
                int p1 = sw ? pB : pA, q1 = sw ? qB : qA;
                int p2 = sw ? pA : pB, q2 = sw ? qA : qB;
                adr0[k] = tidx2(p1,p2); adr1[k] = tidx2(p1,q2);
                adr2[k] = tidx2(q1,p2); adr3[k] = tidx2(q1,q2);
                // unconditional reads (k7-invalid lanes read a valid group
                // owned by another thread; value unused, no write below)
                Bv0[k] = tri[adr0[k]]; Bv1[k] = tri[adr1[k]];
                Bv2[k] = tri[adr2[k]]; Bv3[k] = tri[adr3[k]];
            }

            if (t < NPAIR) {
                float c = 1.f, s = 0.f;
                if (fabsf(apq) > 1e-30f) {
                    float theta = (aqq - app) / (2.f*apq);
                    float tt = 1.f/(fabsf(theta) + sqrtf(theta*theta + 1.f));
                    if (theta < 0.f) tt = -tt;
                    c = 1.f/sqrtf(tt*tt + 1.f);
                    s = tt*c;
                }
                // store rotlog early: maximizes drain time before 2nd barrier
                PackCS pk; pk.f = make_float2(c, s);
                __hip_atomic_store(&g_rotlog[cls][step][t], pk.u,
                                   __ATOMIC_RELAXED, __HIP_MEMORY_SCOPE_AGENT);
                pcs[t] = make_float2(c, s);
                // diagonal 2x2 update (hazard-free: no off-diag group touches these)
                float napp = c*c*app - 2.f*c*s*apq + s*s*aqq;
                float naqq = s*s*app + 2.f*c*s*apq + c*c*aqq;
                tri[tidx(pA,pA)] = napp;
                tri[tidx(qA,qA)] = naqq;
                tri[tidx(qA,pA)] = 0.f;
            }
            __syncthreads();   // pcs + diag updates visible; drains pre-issued reads

            // ---- FMA phase: all operands in registers except (c,s) ----
            float2 csA = pcs[sA];
            #pragma unroll
            for (int k = 0; k < 8; ++k) {
                if (k == 7 && !k7ok) continue;
                float2 csB = pcs[sB[k]];
                bool sw = sB[k] < sA;
                float c1 = sw ? csB.x : csA.x, sv1 = sw ? csB.y : csA.y;
                float c2 = sw ? csA.x : csB.x, sv2 = sw ? csA.y : csB.y;
                float B00 = Bv0[k], B01 = Bv1[k];
                float B10 = Bv2[k], B11 = Bv3[k];
                float X00 = c1*B00 - sv1*B10, X01 = c1*B01 - sv1*B11;
                float X10 = sv1*B00 + c1*B10, X11 = sv1*B01 + c1*B11;
                tri[adr0[k]] = c2*X00 - sv2*X01;
                tri[adr1[k]] = sv2*X00 + c2*X01;
                tri[adr2[k]] = c2*X10 - sv2*X11;
                tri[adr3[k]] = sv2*X10 + c2*X11;
            }
            // advance round-robin state (+1 mod 255; fixed slot stays at 255)
            bA = (bA+1 == NROUND) ? 0 : bA+1;
            if (!zA) aA = (aA+1 == NROUND) ? 0 : aA+1;
            #pragma unroll
            for (int k = 0; k < 8; ++k) {
                bB[k] = (bB[k]+1 == NROUND) ? 0 : bB[k]+1;
                if (!(zBm & (1u<<k))) aB[k] = (aB[k]+1 == NROUND) ? 0 : aB[k]+1;
            }
            __syncthreads();   // drains rotlog store (vmcnt0) + all LDS
            if (t == 0) {
                __hip_atomic_store(&g_step[cls*FLAGSTRIDE], step+1,
                                   __ATOMIC_RELAXED, __HIP_MEMORY_SCOPE_AGENT);
            }
        }
        // publish eigenvalues (agent-scope -> LLC) then release final flag
        for (int f = t; f < FDIM; f += 1024) {
            PackF pf; pf.f = tri[tidx(f,f)];
            __hip_atomic_store((unsigned int*)&g_eval[cls][f], pf.u,
                               __ATOMIC_RELAXED, __HIP_MEMORY_SCOPE_AGENT);
        }
        __syncthreads();       // drains eval stores
        if (t == 0) {
            __hip_atomic_store(&g_step[cls*FLAGSTRIDE], NSTEP+1,
                               __ATOMIC_RELAXED, __HIP_MEMORY_SCOPE_AGENT);
        }
    } else {
        // ======= eigenvector consumer (+ fused sort / W write) =======
        float2* lcs = (float2*)smem;            // 128 packed (c,s)
        float* st = smem + 256;                 // 256 x VST state (64 V-columns)
        float* evbuf = smem + 256 + 256*VST;    // 256 eigenvalues (reuse tail)
        int*   rkbuf = (int*)(evbuf + 256);     // 256 ranks
        int rb = blockIdx.x - NCLS;
        int cls = rb >> 2;
        int ibase = (rb & 3) * 64;

        for (int idx = t; idx < 256*64; idx += 1024) {
            int p = idx >> 6, col = idx & 63;
            st[p*VST + col] = (p == ibase + col) ? 1.f : 0.f;
        }

        int s0 = t >> 5;
        int cp = t & 31;
        // incremental pair state for s_w = s0 + 32w
        int aw[4], bw[4];
        unsigned zwm = 0;
        #pragma unroll
        for (int w = 0; w < 4; ++w) {
            int s = s0 + 32*w;
            bool z = (s == 0);
            if (z) zwm |= 1u << w;
            aw[w] = z ? NROUND : s;
            bw[w] = z ? 0 : NROUND - s;
        }
        __syncthreads();

        for (int step = 0; step < NSTEP; ++step) {
            if (t == 0) {
                while (__hip_atomic_load(&g_step[cls*FLAGSTRIDE], __ATOMIC_RELAXED,
                                         __HIP_MEMORY_SCOPE_AGENT) <= step)
                    __builtin_amdgcn_s_sleep(2);
            }
            __syncthreads();
            if (t < NPAIR) {
                PackCS pk;
                pk.u = __hip_atomic_load(&g_rotlog[cls][step][t],
                                         __ATOMIC_RELAXED, __HIP_MEMORY_SCOPE_AGENT);
                lcs[t] = pk.f;
            }
            __syncthreads();
            float2 xv[4], yv[4];
            float cv[4], sv[4];
            int pa[4], qa[4];
            #pragma unroll
            for (int w = 0; w < 4; ++w) {
                float2 cs = lcs[s0 + 32*w];
                cv[w] = cs.x; sv[w] = cs.y;
                pa[w] = min(aw[w], bw[w]); qa[w] = max(aw[w], bw[w]);
                xv[w] = *(float2*)&st[pa[w]*VST + 2*cp];
                yv[w] = *(float2*)&st[qa[w]*VST + 2*cp];
            }
            #pragma unroll
            for (int w = 0; w < 4; ++w) {
                float2 nx, ny;
                nx.x = cv[w]*xv[w].x - sv[w]*yv[w].x;
                nx.y = cv[w]*xv[w].y - sv[w]*yv[w].y;
                ny.x = sv[w]*xv[w].x + cv[w]*yv[w].x;
                ny.y = sv[w]*xv[w].y + cv[w]*yv[w].y;
                *(float2*)&st[pa[w]*VST + 2*cp] = nx;
                *(float2*)&st[qa[w]*VST + 2*cp] = ny;
            }
            #pragma unroll
            for (int w = 0; w < 4; ++w) {
                bw[w] = (bw[w]+1 == NROUND) ? 0 : bw[w]+1;
                if (!(zwm & (1u<<w))) aw[w] = (aw[w]+1 == NROUND) ? 0 : aw[w]+1;
            }
        }
        // wait for eigenvalues, rank them (identical comparator to old k_sort)
        if (t == 0) {
            while (__hip_atomic_load(&g_step[cls*FLAGSTRIDE], __ATOMIC_RELAXED,
                                     __HIP_MEMORY_SCOPE_AGENT) <= NSTEP)
                __builtin_amdgcn_s_sleep(2);
        }
        __syncthreads();
        if (t < 256) {
            PackF pf;
            pf.u = __hip_atomic_load((unsigned int*)&g_eval[cls][t],
                                     __ATOMIC_RELAXED, __HIP_MEMORY_SCOPE_AGENT);
            evbuf[t] = pf.f;
        }
        __syncthreads();
        if (t < 256) {
            float mine = evbuf[t];
            int r = 0;
            for (int f = 0; f < 256; ++f) {
                float o = evbuf[f];
                if (o > mine || (o == mine && f < t)) ++r;
            }
            rkbuf[t] = r;
        }
        __syncthreads();
        for (int idx = t; idx < 256*32; idx += 1024) {
            int f = idx >> 5, c2 = idx & 31;
            float2 v = *(float2*)&st[f*VST + 2*c2];
            *(float2*)&g_W[cls][rkbuf[f]][ibase + 2*c2] = v;
        }
    }
}

// ---- K10: M[c] = proj @ W[c]   (D x F) ----
__global__ void k_mgemm(const float* __restrict__ pm) {
    int cls = blockIdx.z, dt = blockIdx.y, gt = blockIdx.x;
    __shared__ float At[64][17], Bt[16][65];
    int t = threadIdx.x, tx = t & 15, ty = t >> 4;
    float accv[4][4] = {};
    for (int k0 = 0; k0 < FDIM; k0 += 16) {
        #pragma unroll
        for (int l = 0; l < 4; ++l) {
            int idx = t*4 + l;
            int row = idx >> 4, col = idx & 15;
            At[row][col] = pm[(size_t)(dt*64+row)*FDIM + k0 + col];
        }
        #pragma unroll
        for (int l = 0; l < 4; ++l) {
            int idx = t*4 + l;
            int row = idx >> 6, col = idx & 63;
            Bt[row][col] = g_W[cls][k0+row][gt*64+col];
        }
        __syncthreads();
        #pragma unroll
        for (int kk = 0; kk < 16; ++kk) {
            float a[4], b[4];
            #pragma unroll
            for (int i = 0; i < 4; ++i) a[i] = At[ty*4+i][kk];
            #pragma unroll
            for (int j = 0; j < 4; ++j) b[j] = Bt[kk][tx*4+j];
            #pragma unroll
            for (int i = 0; i < 4; ++i)
                #pragma unroll
                for (int j = 0; j < 4; ++j) accv[i][j] += a[i]*b[j];
        }
        __syncthreads();
    }
    #pragma unroll
    for (int i = 0; i < 4; ++i)
        #pragma unroll
        for (int j = 0; j < 4; ++j)
            g_M[cls][dt*64+ty*4+i][gt*64+tx*4+j] = accv[i][j];
}

// ---- K11: fv = M[c] @ Xc, accumulate moments m1..m4 over columns ----
__global__ void k_fvmom() {
    int cls = blockIdx.y, dt = blockIdx.x;
    __shared__ float Mt[64][17], Xt[16][65];
    __shared__ float red[64][16];
    int t = threadIdx.x, tx = t & 15, ty = t >> 4;
    float mm[4][4] = {};
    for (int kt = 0; kt < KPAD; kt += 64) {
        float accv[4][4] = {};
        for (int g0 = 0; g0 < FDIM; g0 += 16) {
            #pragma unroll
            for (int l = 0; l < 4; ++l) {
                int idx = t*4 + l;
                int row = idx >> 4, col = idx & 15;
                Mt[row][col] = g_M[cls][dt*64+row][g0+col];
            }
            #pragma unroll
            for (int l = 0; l < 4; ++l) {
                int idx = t*4 + l;
                int row = idx >> 6, col = idx & 63;
                Xt[row][col] = g_X[cls][g0+row][kt+col];
            }
            __syncthreads();
            #pragma unroll
            for (int kk = 0; kk < 16; ++kk) {
                float a[4], b[4];
                #pragma unroll
                for (int i = 0; i < 4; ++i) a[i] = Mt[ty*4+i][kk];
                #pragma unroll
                for (int j = 0; j < 4; ++j) b[j] = Xt[kk][tx*4+j];
                #pragma unroll
                for (int i = 0; i < 4; ++i)
                    #pragma unroll
                    for (int j = 0; j < 4; ++j) accv[i][j] += a[i]*b[j];
            }
            __syncthreads();
        }
        #pragma unroll
        for (int i = 0; i < 4; ++i)
            #pragma unroll
            for (int j = 0; j < 4; ++j) {
                float v = accv[i][j], v2 = v*v;
                mm[0][i] += v; mm[1][i] += v2; mm[2][i] += v2*v; mm[3][i] += v2*v2;
            }
    }
    #pragma unroll
    for (int m = 0; m < 4; ++m) {
        __syncthreads();
        #pragma unroll
        for (int i = 0; i < 4; ++i) red[ty*4+i][tx] = mm[m][i];
        __syncthreads();
        if (t < 64) {
            float s = 0.f;
            #pragma unroll
            for (int x = 0; x < 16; ++x) s += red[t][x];
            g_mom[cls][dt*64 + t][m] = s;
        }
    }
}

// ---- K12: kurtosis, clip, weighted mean -> loss ----
__global__ __launch_bounds__(1024) void k_loss(float* __restrict__ out) {
    __shared__ float red[1024];
    int t = threadIdx.x;
    float sum = 0.f;
    for (int id = t; id < NCLS*DDIR; id += 1024) {
        int c = id >> 10, d = id & 1023;
        float cntv = g_cntf[c];
        if (cntv > 0.f) {
            float invns = 1.f / g_ns[c];
            float m1 = g_mom[c][d][0]*invns;
            float m2 = g_mom[c][d][1]*invns;
            float m3 = g_mom[c][d][2]*invns;
            float m4 = g_mom[c][d][3]*invns;
            float var = fmaxf(m2 - m1*m1, 1e-16f);
            float m4c = -3.f*m1*m1*m1*m1 + 6.f*m2*m1*m1 - 4.f*m3*m1 + m4;
            float kurt = m4c/(var*var) - 3.f;
            kurt = fminf(fmaxf(kurt, -3.f), 3.f);
            sum += kurt*kurt;
        }
    }
    red[t] = sum;
    __syncthreads();
    for (int off = 512; off > 0; off >>= 1) {
        if (t < off) red[t] += red[t+off];
        __syncthreads();
    }
    if (t == 0) {
        float na = 0.f;
        for (int c = 0; c < NCLS; ++c) na += (g_cntf[c] > 0.f) ? 1.f : 0.f;
        na = fmaxf(na, 1.f);
        out[0] = red[0] / ((float)DDIR * na);
    }
}

extern "C" void kernel_launch(void* const* d_in, const int* in_sizes, int n_in,
                              void* d_out, int out_size, void* d_ws, size_t ws_size,
                              hipStream_t stream) {
    const float* feat = (const float*)d_in[0];
    const int*   lab  = (const int*)d_in[1];
    const float* pm   = (const float*)d_in[2];
    float* out = (float*)d_out;

    const int eig_lds = (256 + TRI_N) * 4 + 64;   // producer needs the max

    (void)hipFuncSetAttribute((const void*)k_eigen,
        hipFuncAttributeMaxDynamicSharedMemorySize, eig_lds);

    hipLaunchKernelGGL(k_zero, dim3(3648), dim3(1024), 0, stream);
    hipLaunchKernelGGL(k_sums, dim3(256), dim3(256), 0, stream, feat, lab);
    hipLaunchKernelGGL(k_rank, dim3(NSEG), dim3(256), 0, stream, lab);
    hipLaunchKernelGGL(k_segscan, dim3(1), dim3(64), 0, stream);
    hipLaunchKernelGGL(k_scatter, dim3(32, 256), dim3(256), 0, stream, feat, lab);
    hipLaunchKernelGGL(k_covgemm, dim3(4, 4, NCLS), dim3(256), 0, stream);
    hipLaunchKernelGGL(k_eigen, dim3(NCLS + NCLS*4), dim3(1024), eig_lds, stream);
    hipLaunchKernelGGL(k_mgemm, dim3(4, 16, NCLS), dim3(256), 0, stream, pm);
    hipLaunchKernelGGL(k_fvmom, dim3(16, NCLS), dim3(256), 0, stream);
    hipLaunchKernelGGL(k_loss, dim3(1), dim3(1024), 0, stream, out);
}

// Round 6
// 4682.895 us; speedup vs baseline: 1.2917x; 1.2318x over previous
//
#include <hip/hip_runtime.h>
#include <math.h>

// Problem constants
#define NCLS 19
#define FDIM 256
#define DDIR 1024
#define NPIX 8192
#define KPAD 768            // per-class compacted-column padding (max n_c ~ 500)
#define NSWEEP 5
#define NROUND 255
#define NSTEP (NSWEEP*NROUND)
#define NPAIR 128
#define TRI_N 32896         // 256*257/2 packed triangular size
#define NOFF 8128           // 128*127/2 off-diagonal group pairs (s1<s2)
#define NSEG 32             // 8192 / 256 label segments
#define VST 66              // replay V-state row stride (64 + 2 pad)
#define FLAGSTRIDE 16       // pad step-flags to 64B lines

// ---- device-global workspace ----
__device__ float g_cntf[NCLS];
__device__ float g_ns[NCLS];
__device__ float g_mu[NCLS][FDIM];
__device__ int   g_rank[NPIX];
__device__ int   g_segcnt[NSEG][NCLS];
__device__ int   g_segoff[NSEG][NCLS];
__device__ float g_X[NCLS][FDIM][KPAD];
__device__ float g_cov[NCLS][FDIM][FDIM];
__device__ unsigned long long g_rotlog[NCLS][NSTEP][NPAIR];  // packed (c,s)
__device__ int   g_step[NCLS*FLAGSTRIDE];
__device__ float g_eval[NCLS][FDIM];
__device__ float g_W[NCLS][FDIM][FDIM];
__device__ float g_M[NCLS][DDIR][FDIM];
__device__ float g_mom[NCLS][DDIR][4];

union PackCS { float2 f; unsigned long long u; };
union PackF  { float f; unsigned int u; };

// round-robin tournament pairing: 255 fixed, 0..254 rotate
__device__ __forceinline__ void get_pair(int r, int s, int& p, int& q) {
    int a, b;
    if (s == 0) { a = NROUND; b = r; }
    else {
        a = r + s; if (a >= NROUND) a -= NROUND;
        b = r - s; if (b < 0) b += NROUND;
    }
    p = min(a, b); q = max(a, b);
}

// Packed triangular addressing (R1 layout/structure — empirically fastest at
// 4258us. R2 swizzle, R3 row-padding, R4 read-batching, R5 prefetch-across-
// barrier (spilled, VGPR capped at 56) ALL regressed to 5250-5530us. Do not
// perturb the producer codegen without disasm evidence.)
__device__ __forceinline__ int tidx(int i, int j) { return ((i*(i+1))>>1) + j; } // i>=j
__device__ __forceinline__ int tidx2(int a, int b) { return a >= b ? tidx(a,b) : tidx(b,a); }

// ---- K0: zero compacted buffer + flags + segment counters ----
__global__ __launch_bounds__(1024) void k_zero() {
    int idx = blockIdx.x*blockDim.x + threadIdx.x;
    const int total = NCLS*FDIM*KPAD;
    float* x = &g_X[0][0][0];
    for (int i = idx; i < total; i += gridDim.x*blockDim.x) x[i] = 0.f;
    if (idx < NCLS*FLAGSTRIDE) g_step[idx] = 0;
    if (idx < NSEG*NCLS) (&g_segcnt[0][0])[idx] = 0;
}

// ---- K1: per-class sums per feature + counts; writes mu/ns directly ----
__global__ void k_sums(const float* __restrict__ feat, const int* __restrict__ lab) {
    __shared__ float acc[NCLS][256];
    __shared__ float cnt[NCLS][256];
    int t = threadIdx.x;
    int f = blockIdx.x;
    for (int c = 0; c < NCLS; ++c) { acc[c][t] = 0.f; cnt[c][t] = 0.f; }
    for (int j = 0; j < NPIX/256; ++j) {
        int n = t + 256*j;
        int b = n >> 12, hw = n & 4095;
        float v = feat[(size_t)b*1048576 + (size_t)f*4096 + hw];
        int c = lab[n];
        acc[c][t] += v;
        cnt[c][t] += 1.f;
    }
    __syncthreads();
    for (int off = 128; off > 0; off >>= 1) {
        if (t < off)
            for (int c = 0; c < NCLS; ++c) {
                acc[c][t] += acc[c][t+off];
                cnt[c][t] += cnt[c][t+off];
            }
        __syncthreads();
    }
    if (t < NCLS) {
        float ns = fmaxf(cnt[t][0], 1.f);
        g_mu[t][f] = acc[t][0] / ns;      // identical operands/order as old musetup
        if (f == 0) { g_cntf[t] = cnt[t][0]; g_ns[t] = ns; }
    }
}

// ---- K3a: deterministic per-segment rank + per-segment class counts ----
__global__ void k_rank(const int* __restrict__ lab) {
    __shared__ int sl[256];
    int seg = blockIdx.x, t = threadIdx.x;
    int n = seg*256 + t;
    int c = lab[n];
    sl[t] = c;
    __syncthreads();
    int rnk = 0, tot = 0;
    for (int i = 0; i < 256; ++i) {
        int e = sl[i];
        if (e == c) { tot += 1; if (i < t) rnk += 1; }
    }
    g_rank[n] = rnk;
    if (rnk == 0) g_segcnt[seg][c] = tot;
}

// ---- K3b: exclusive scan of segment counts per class ----
__global__ void k_segscan() {
    int c = threadIdx.x;
    if (c < NCLS) {
        int run = 0;
        for (int s = 0; s < NSEG; ++s) {
            g_segoff[s][c] = run;
            run += g_segcnt[s][c];
        }
    }
}

// ---- K4: scatter centered features into per-class compacted matrix ----
__global__ void k_scatter(const float* __restrict__ feat, const int* __restrict__ lab) {
    int n = blockIdx.x*256 + threadIdx.x;
    int g = blockIdx.y;
    int c = lab[n];
    int pos = g_segoff[n >> 8][c] + g_rank[n];
    float v = feat[(size_t)(n>>12)*1048576 + (size_t)g*4096 + (n&4095)] - g_mu[c][g];
    g_X[c][g][pos] = v;
}

// ---- K5: cov = (Xc Xc^T)/ns ----
// Dynamic K bound: columns beyond n_c are exact zeros (k_zero + scatter), and
// accumulating x += 0.f*0.f is bit-identical to skipping it. Truncate the K
// loop to n_c rounded up to the 16-wide tile -> ~40% less work, same bits.
__global__ void k_covgemm() {
    int cls = blockIdx.z, ti = blockIdx.y, tj = blockIdx.x;
    __shared__ float At[64][17], Bt[64][17];
    int t = threadIdx.x, tx = t & 15, ty = t >> 4;
    int kc = min(KPAD, (((int)g_cntf[cls]) + 15) & ~15);
    float accv[4][4] = {};
    for (int k0 = 0; k0 < kc; k0 += 16) {
        #pragma unroll
        for (int l = 0; l < 4; ++l) {
            int idx = t*4 + l;
            int row = idx >> 4, col = idx & 15;
            At[row][col] = g_X[cls][ti*64+row][k0+col];
            Bt[row][col] = g_X[cls][tj*64+row][k0+col];
        }
        __syncthreads();
        #pragma unroll
        for (int kk = 0; kk < 16; ++kk) {
            float a[4], b[4];
            #pragma unroll
            for (int i = 0; i < 4; ++i) a[i] = At[ty*4+i][kk];
            #pragma unroll
            for (int j = 0; j < 4; ++j) b[j] = Bt[tx*4+j][kk];
            #pragma unroll
            for (int i = 0; i < 4; ++i)
                #pragma unroll
                for (int j = 0; j < 4; ++j) accv[i][j] += a[i]*b[j];
        }
        __syncthreads();
    }
    float invns = 1.f / g_ns[cls];
    #pragma unroll
    for (int i = 0; i < 4; ++i)
        #pragma unroll
        for (int j = 0; j < 4; ++j)
            g_cov[cls][ti*64+ty*4+i][tj*64+tx*4+j] = accv[i][j]*invns;
}

// ---- K6: FUSED eigensolver (producer = Jacobi, consumer = V accumulation
//          + fused eigen-sort / W write) ----
__global__ __launch_bounds__(1024) void k_eigen() {
    extern __shared__ float smem[];
    int t = threadIdx.x;

    if (blockIdx.x < NCLS) {
        // ================= Jacobi producer =================
        float2* pcs = (float2*)smem;  // 128 packed (c,s) -> 256-float footprint
        float* tri  = smem + 256;     // TRI_N floats (packed layout)
        int cls = blockIdx.x;

        for (int L = t; L < TRI_N; L += 1024) {
            int i = (int)((sqrtf(8.f*L+1.f)-1.f)*0.5f);
            while ((i+1)*(i+2)/2 <= L) ++i;
            while (i*(i+1)/2 > L) --i;
            int j = L - i*(i+1)/2;
            tri[L] = g_cov[cls][i][j];
        }

        // Fixed-sA group mapping: thread rotates its own pair-index sA against
        // 8 partners sB = (sA + d) & 127 with d = 8k + h + 1 in 1..64.
        // Coverage: d=1..63 over all 128 origins covers each unordered group
        // once; d=64 (k==7,h==7) restricted to sA<64. Total = 8064+64 = 8128.
        // Skip pattern is wave-uniform (wave 15 skips k=7 entirely).
        const int sA = t & 127;
        const int h  = t >> 7;
        const bool k7ok = (h != 7) || (sA < 64);
        int sB[8];
        #pragma unroll
        for (int k = 0; k < 8; ++k) sB[k] = (sA + 8*k + h + 1) & 127;

        // Incremental round-robin state: for pair index s, a=(r+s)%255 (or 255
        // fixed when s==0), b=(r-s)%255; both advance +1 mod 255 per step.
        const bool zA = (sA == 0);
        int aA = zA ? NROUND : sA;
        int bA = zA ? 0 : NROUND - sA;
        int aB[8], bB[8];
        unsigned zBm = 0;
        #pragma unroll
        for (int k = 0; k < 8; ++k) {
            bool z = (sB[k] == 0);
            if (z) zBm |= 1u << k;
            aB[k] = z ? NROUND : sB[k];
            bB[k] = z ? 0 : NROUND - sB[k];
        }
        __syncthreads();

        for (int step = 0; step < NSTEP; ++step) {
            int r = step % NROUND;
            if (t < NPAIR) {
                int p, q; get_pair(r, t, p, q);
                float app = tri[tidx(p,p)], aqq = tri[tidx(q,q)], apq = tri[tidx(q,p)];
                float c = 1.f, s = 0.f;
                if (fabsf(apq) > 1e-30f) {
                    float theta = (aqq - app) / (2.f*apq);
                    float tt = 1.f/(fabsf(theta) + sqrtf(theta*theta + 1.f));
                    if (theta < 0.f) tt = -tt;
                    c = 1.f/sqrtf(tt*tt + 1.f);
                    s = tt*c;
                }
                // store rotlog early: maximizes drain time before 2nd barrier
                PackCS pk; pk.f = make_float2(c, s);
                __hip_atomic_store(&g_rotlog[cls][step][t], pk.u,
                                   __ATOMIC_RELAXED, __HIP_MEMORY_SCOPE_AGENT);
                pcs[t] = make_float2(c, s);
                // diagonal 2x2 update (hazard-free: no off-diag group touches these)
                float napp = c*c*app - 2.f*c*s*apq + s*s*aqq;
                float naqq = s*s*app + 2.f*c*s*apq + c*c*aqq;
                tri[tidx(p,p)] = napp;
                tri[tidx(q,q)] = naqq;
                tri[tidx(q,p)] = 0.f;
            }
            __syncthreads();   // pcs + diag updates visible

            int pA = min(aA, bA), qA = max(aA, bA);
            float2 csA = pcs[sA];
            #pragma unroll
            for (int k = 0; k < 8; ++k) {
                if (k == 7 && !k7ok) continue;
                int pB = min(aB[k], bB[k]), qB = max(aB[k], bB[k]);
                float2 csB = pcs[sB[k]];
                // preserve original role order: smaller pair index acts on rows
                bool sw = sB[k] < sA;
                int p1 = sw ? pB : pA, q1 = sw ? qB : qA;
                int p2 = sw ? pA : pB, q2 = sw ? qA : qB;
                float c1 = sw ? csB.x : csA.x, sv1 = sw ? csB.y : csA.y;
                float c2 = sw ? csA.x : csB.x, sv2 = sw ? csA.y : csB.y;
                int i00 = tidx2(p1,p2), i01 = tidx2(p1,q2);
                int i10 = tidx2(q1,p2), i11 = tidx2(q1,q2);
                float B00 = tri[i00], B01 = tri[i01];
                float B10 = tri[i10], B11 = tri[i11];
                float X00 = c1*B00 - sv1*B10, X01 = c1*B01 - sv1*B11;
                float X10 = sv1*B00 + c1*B10, X11 = sv1*B01 + c1*B11;
                tri[i00] = c2*X00 - sv2*X01;
                tri[i01] = sv2*X00 + c2*X01;
                tri[i10] = c2*X10 - sv2*X11;
                tri[i11] = sv2*X10 + c2*X11;
            }
            // advance round-robin state (+1 mod 255; fixed slot stays at 255)
            bA = (bA+1 == NROUND) ? 0 : bA+1;
            if (!zA) aA = (aA+1 == NROUND) ? 0 : aA+1;
            #pragma unroll
            for (int k = 0; k < 8; ++k) {
                bB[k] = (bB[k]+1 == NROUND) ? 0 : bB[k]+1;
                if (!(zBm & (1u<<k))) aB[k] = (aB[k]+1 == NROUND) ? 0 : aB[k]+1;
            }
            __syncthreads();   // drains rotlog store (vmcnt0) + all LDS
            if (t == 0) {
                __hip_atomic_store(&g_step[cls*FLAGSTRIDE], step+1,
                                   __ATOMIC_RELAXED, __HIP_MEMORY_SCOPE_AGENT);
            }
        }
        // publish eigenvalues (agent-scope -> LLC) then release final flag
        for (int f = t; f < FDIM; f += 1024) {
            PackF pf; pf.f = tri[tidx(f,f)];
            __hip_atomic_store((unsigned int*)&g_eval[cls][f], pf.u,
                               __ATOMIC_RELAXED, __HIP_MEMORY_SCOPE_AGENT);
        }
        __syncthreads();       // drains eval stores
        if (t == 0) {
            __hip_atomic_store(&g_step[cls*FLAGSTRIDE], NSTEP+1,
                               __ATOMIC_RELAXED, __HIP_MEMORY_SCOPE_AGENT);
        }
    } else {
        // ======= eigenvector consumer (+ fused sort / W write) =======
        float2* lcs = (float2*)smem;            // 128 packed (c,s)
        float* st = smem + 256;                 // 256 x VST state (64 V-columns)
        float* evbuf = smem + 256 + 256*VST;    // 256 eigenvalues (reuse tail)
        int*   rkbuf = (int*)(evbuf + 256);     // 256 ranks
        int rb = blockIdx.x - NCLS;
        int cls = rb >> 2;
        int ibase = (rb & 3) * 64;

        for (int idx = t; idx < 256*64; idx += 1024) {
            int p = idx >> 6, col = idx & 63;
            st[p*VST + col] = (p == ibase + col) ? 1.f : 0.f;
        }

        int s0 = t >> 5;
        int cp = t & 31;
        // incremental pair state for s_w = s0 + 32w
        int aw[4], bw[4];
        unsigned zwm = 0;
        #pragma unroll
        for (int w = 0; w < 4; ++w) {
            int s = s0 + 32*w;
            bool z = (s == 0);
            if (z) zwm |= 1u << w;
            aw[w] = z ? NROUND : s;
            bw[w] = z ? 0 : NROUND - s;
        }
        __syncthreads();

        for (int step = 0; step < NSTEP; ++step) {
            if (t == 0) {
                while (__hip_atomic_load(&g_step[cls*FLAGSTRIDE], __ATOMIC_RELAXED,
                                         __HIP_MEMORY_SCOPE_AGENT) <= step)
                    __builtin_amdgcn_s_sleep(2);
            }
            __syncthreads();
            if (t < NPAIR) {
                PackCS pk;
                pk.u = __hip_atomic_load(&g_rotlog[cls][step][t],
                                         __ATOMIC_RELAXED, __HIP_MEMORY_SCOPE_AGENT);
                lcs[t] = pk.f;
            }
            __syncthreads();
            float2 xv[4], yv[4];
            float cv[4], sv[4];
            int pa[4], qa[4];
            #pragma unroll
            for (int w = 0; w < 4; ++w) {
                float2 cs = lcs[s0 + 32*w];
                cv[w] = cs.x; sv[w] = cs.y;
                pa[w] = min(aw[w], bw[w]); qa[w] = max(aw[w], bw[w]);
                xv[w] = *(float2*)&st[pa[w]*VST + 2*cp];
                yv[w] = *(float2*)&st[qa[w]*VST + 2*cp];
            }
            #pragma unroll
            for (int w = 0; w < 4; ++w) {
                float2 nx, ny;
                nx.x = cv[w]*xv[w].x - sv[w]*yv[w].x;
                nx.y = cv[w]*xv[w].y - sv[w]*yv[w].y;
                ny.x = sv[w]*xv[w].x + cv[w]*yv[w].x;
                ny.y = sv[w]*xv[w].y + cv[w]*yv[w].y;
                *(float2*)&st[pa[w]*VST + 2*cp] = nx;
                *(float2*)&st[qa[w]*VST + 2*cp] = ny;
            }
            #pragma unroll
            for (int w = 0; w < 4; ++w) {
                bw[w] = (bw[w]+1 == NROUND) ? 0 : bw[w]+1;
                if (!(zwm & (1u<<w))) aw[w] = (aw[w]+1 == NROUND) ? 0 : aw[w]+1;
            }
        }
        // wait for eigenvalues, rank them (identical comparator to old k_sort)
        if (t == 0) {
            while (__hip_atomic_load(&g_step[cls*FLAGSTRIDE], __ATOMIC_RELAXED,
                                     __HIP_MEMORY_SCOPE_AGENT) <= NSTEP)
                __builtin_amdgcn_s_sleep(2);
        }
        __syncthreads();
        if (t < 256) {
            PackF pf;
            pf.u = __hip_atomic_load((unsigned int*)&g_eval[cls][t],
                                     __ATOMIC_RELAXED, __HIP_MEMORY_SCOPE_AGENT);
            evbuf[t] = pf.f;
        }
        __syncthreads();
        if (t < 256) {
            float mine = evbuf[t];
            int r = 0;
            for (int f = 0; f < 256; ++f) {
                float o = evbuf[f];
                if (o > mine || (o == mine && f < t)) ++r;
            }
            rkbuf[t] = r;
        }
        __syncthreads();
        for (int idx = t; idx < 256*32; idx += 1024) {
            int f = idx >> 5, c2 = idx & 31;
            float2 v = *(float2*)&st[f*VST + 2*c2];
            *(float2*)&g_W[cls][rkbuf[f]][ibase + 2*c2] = v;
        }
    }
}

// ---- K10: M[c] = proj @ W[c]   (D x F) ----
__global__ void k_mgemm(const float* __restrict__ pm) {
    int cls = blockIdx.z, dt = blockIdx.y, gt = blockIdx.x;
    __shared__ float At[64][17], Bt[16][65];
    int t = threadIdx.x, tx = t & 15, ty = t >> 4;
    float accv[4][4] = {};
    for (int k0 = 0; k0 < FDIM; k0 += 16) {
        #pragma unroll
        for (int l = 0; l < 4; ++l) {
            int idx = t*4 + l;
            int row = idx >> 4, col = idx & 15;
            At[row][col] = pm[(size_t)(dt*64+row)*FDIM + k0 + col];
        }
        #pragma unroll
        for (int l = 0; l < 4; ++l) {
            int idx = t*4 + l;
            int row = idx >> 6, col = idx & 63;
            Bt[row][col] = g_W[cls][k0+row][gt*64+col];
        }
        __syncthreads();
        #pragma unroll
        for (int kk = 0; kk < 16; ++kk) {
            float a[4], b[4];
            #pragma unroll
            for (int i = 0; i < 4; ++i) a[i] = At[ty*4+i][kk];
            #pragma unroll
            for (int j = 0; j < 4; ++j) b[j] = Bt[kk][tx*4+j];
            #pragma unroll
            for (int i = 0; i < 4; ++i)
                #pragma unroll
                for (int j = 0; j < 4; ++j) accv[i][j] += a[i]*b[j];
        }
        __syncthreads();
    }
    #pragma unroll
    for (int i = 0; i < 4; ++i)
        #pragma unroll
        for (int j = 0; j < 4; ++j)
            g_M[cls][dt*64+ty*4+i][gt*64+tx*4+j] = accv[i][j];
}

// ---- K11: fv = M[c] @ Xc, accumulate moments m1..m4 over columns ----
// Dynamic K bound (same argument as k_covgemm): columns >= n_c give accv = 0
// exactly, and adding v=0, v2=0 to the moment accumulators is bit-identical
// to skipping the tile. Truncate kt to n_c rounded up to 64.
__global__ void k_fvmom() {
    int cls = blockIdx.y, dt = blockIdx.x;
    __shared__ float Mt[64][17], Xt[16][65];
    __shared__ float red[64][16];
    int t = threadIdx.x, tx = t & 15, ty = t >> 4;
    int kc = min(KPAD, (((int)g_cntf[cls]) + 63) & ~63);
    float mm[4][4] = {};
    for (int kt = 0; kt < kc; kt += 64) {
        float accv[4][4] = {};
        for (int g0 = 0; g0 < FDIM; g0 += 16) {
            #pragma unroll
            for (int l = 0; l < 4; ++l) {
                int idx = t*4 + l;
                int row = idx >> 4, col = idx & 15;
                Mt[row][col] = g_M[cls][dt*64+row][g0+col];
            }
            #pragma unroll
            for (int l = 0; l < 4; ++l) {
                int idx = t*4 + l;
                int row = idx >> 6, col = idx & 63;
                Xt[row][col] = g_X[cls][g0+row][kt+col];
            }
            __syncthreads();
            #pragma unroll
            for (int kk = 0; kk < 16; ++kk) {
                float a[4], b[4];
                #pragma unroll
                for (int i = 0; i < 4; ++i) a[i] = Mt[ty*4+i][kk];
                #pragma unroll
                for (int j = 0; j < 4; ++j) b[j] = Xt[kk][tx*4+j];
                #pragma unroll
                for (int i = 0; i < 4; ++i)
                    #pragma unroll
                    for (int j = 0; j < 4; ++j) accv[i][j] += a[i]*b[j];
            }
            __syncthreads();
        }
        #pragma unroll
        for (int i = 0; i < 4; ++i)
            #pragma unroll
            for (int j = 0; j < 4; ++j) {
                float v = accv[i][j], v2 = v*v;
                mm[0][i] += v; mm[1][i] += v2; mm[2][i] += v2*v; mm[3][i] += v2*v2;
            }
    }
    #pragma unroll
    for (int m = 0; m < 4; ++m) {
        __syncthreads();
        #pragma unroll
        for (int i = 0; i < 4; ++i) red[ty*4+i][tx] = mm[m][i];
        __syncthreads();
        if (t < 64) {
            float s = 0.f;
            #pragma unroll
            for (int x = 0; x < 16; ++x) s += red[t][x];
            g_mom[cls][dt*64 + t][m] = s;
        }
    }
}

// ---- K12: kurtosis, clip, weighted mean -> loss ----
__global__ __launch_bounds__(1024) void k_loss(float* __restrict__ out) {
    __shared__ float red[1024];
    int t = threadIdx.x;
    float sum = 0.f;
    for (int id = t; id < NCLS*DDIR; id += 1024) {
        int c = id >> 10, d = id & 1023;
        float cntv = g_cntf[c];
        if (cntv > 0.f) {
            float invns = 1.f / g_ns[c];
            float m1 = g_mom[c][d][0]*invns;
            float m2 = g_mom[c][d][1]*invns;
            float m3 = g_mom[c][d][2]*invns;
            float m4 = g_mom[c][d][3]*invns;
            float var = fmaxf(m2 - m1*m1, 1e-16f);
            float m4c = -3.f*m1*m1*m1*m1 + 6.f*m2*m1*m1 - 4.f*m3*m1 + m4;
            float kurt = m4c/(var*var) - 3.f;
            kurt = fminf(fmaxf(kurt, -3.f), 3.f);
            sum += kurt*kurt;
        }
    }
    red[t] = sum;
    __syncthreads();
    for (int off = 512; off > 0; off >>= 1) {
        if (t < off) red[t] += red[t+off];
        __syncthreads();
    }
    if (t == 0) {
        float na = 0.f;
        for (int c = 0; c < NCLS; ++c) na += (g_cntf[c] > 0.f) ? 1.f : 0.f;
        na = fmaxf(na, 1.f);
        out[0] = red[0] / ((float)DDIR * na);
    }
}

extern "C" void kernel_launch(void* const* d_in, const int* in_sizes, int n_in,
                              void* d_out, int out_size, void* d_ws, size_t ws_size,
                              hipStream_t stream) {
    const float* feat = (const float*)d_in[0];
    const int*   lab  = (const int*)d_in[1];
    const float* pm   = (const float*)d_in[2];
    float* out = (float*)d_out;

    const int eig_lds = (256 + TRI_N) * 4 + 64;   // producer needs the max

    (void)hipFuncSetAttribute((const void*)k_eigen,
        hipFuncAttributeMaxDynamicSharedMemorySize, eig_lds);

    hipLaunchKernelGGL(k_zero, dim3(3648), dim3(1024), 0, stream);
    hipLaunchKernelGGL(k_sums, dim3(256), dim3(256), 0, stream, feat, lab);
    hipLaunchKernelGGL(k_rank, dim3(NSEG), dim3(256), 0, stream, lab);
    hipLaunchKernelGGL(k_segscan, dim3(1), dim3(64), 0, stream);
    hipLaunchKernelGGL(k_scatter, dim3(32, 256), dim3(256), 0, stream, feat, lab);
    hipLaunchKernelGGL(k_covgemm, dim3(4, 4, NCLS), dim3(256), 0, stream);
    hipLaunchKernelGGL(k_eigen, dim3(NCLS + NCLS*4), dim3(1024), eig_lds, stream);
    hipLaunchKernelGGL(k_mgemm, dim3(4, 16, NCLS), dim3(256), 0, stream, pm);
    hipLaunchKernelGGL(k_fvmom, dim3(16, NCLS), dim3(256), 0, stream);
    hipLaunchKernelGGL(k_loss, dim3(1), dim3(1024), 0, stream, out);
}

// Round 7
// 3975.412 us; speedup vs baseline: 1.5215x; 1.1780x over previous
//
#include <hip/hip_runtime.h>
#include <math.h>

// Problem constants
#define NCLS 19
#define FDIM 256
#define DDIR 1024
#define NPIX 8192
#define KPAD 768            // per-class compacted-column padding (max n_c ~ 500)
#define NSWEEP 5
#define NPAIR 128
#define NSTEP2 (NSWEEP*256) // 1280 odd-even-transposition rounds (= 5 full sweeps)
#define TRI_N 32896         // 256*257/2 packed triangular size
#define NSEG 32             // 8192 / 256 label segments
#define VST 66              // replay V-state row stride (64 + 2 pad)
#define FLAGSTRIDE 16       // pad step-flags to 64B lines

// ---- device-global workspace ----
__device__ float g_cntf[NCLS];
__device__ float g_ns[NCLS];
__device__ float g_mu[NCLS][FDIM];
__device__ int   g_rank[NPIX];
__device__ int   g_segcnt[NSEG][NCLS];
__device__ int   g_segoff[NSEG][NCLS];
__device__ float g_X[NCLS][FDIM][KPAD];
__device__ float g_cov[NCLS][FDIM][FDIM];
__device__ unsigned long long g_rotlog[NCLS][NSTEP2][NPAIR];  // packed (c,s)
__device__ int   g_step[NCLS*FLAGSTRIDE];
__device__ float g_eval[NCLS][FDIM];
__device__ float g_W[NCLS][FDIM][FDIM];
__device__ float g_M[NCLS][DDIR][FDIM];
__device__ float g_mom[NCLS][DDIR][4];

union PackCS { float2 f; unsigned long long u; };
union PackF  { float f; unsigned int u; };

// Packed triangular addressing. Producer per-step cost is LDS wave-instruction
// count (m134: ~5.8cy/op mostly per-op overhead) — R2-R5 proved conflicts and
// latency are NOT the bound. The odd-even pairing below makes every accessed
// element pair ADJACENT so the compiler can fuse to ds_read2/write2_b32,
// halving the op count.
__device__ __forceinline__ int tidx(int i, int j) { return ((i*(i+1))>>1) + j; } // i>=j

// ---- K0: zero compacted buffer + flags + segment counters ----
__global__ __launch_bounds__(1024) void k_zero() {
    int idx = blockIdx.x*blockDim.x + threadIdx.x;
    const int total = NCLS*FDIM*KPAD;
    float* x = &g_X[0][0][0];
    for (int i = idx; i < total; i += gridDim.x*blockDim.x) x[i] = 0.f;
    if (idx < NCLS*FLAGSTRIDE) g_step[idx] = 0;
    if (idx < NSEG*NCLS) (&g_segcnt[0][0])[idx] = 0;
}

// ---- K1: per-class sums per feature + counts; writes mu/ns directly ----
__global__ void k_sums(const float* __restrict__ feat, const int* __restrict__ lab) {
    __shared__ float acc[NCLS][256];
    __shared__ float cnt[NCLS][256];
    int t = threadIdx.x;
    int f = blockIdx.x;
    for (int c = 0; c < NCLS; ++c) { acc[c][t] = 0.f; cnt[c][t] = 0.f; }
    for (int j = 0; j < NPIX/256; ++j) {
        int n = t + 256*j;
        int b = n >> 12, hw = n & 4095;
        float v = feat[(size_t)b*1048576 + (size_t)f*4096 + hw];
        int c = lab[n];
        acc[c][t] += v;
        cnt[c][t] += 1.f;
    }
    __syncthreads();
    for (int off = 128; off > 0; off >>= 1) {
        if (t < off)
            for (int c = 0; c < NCLS; ++c) {
                acc[c][t] += acc[c][t+off];
                cnt[c][t] += cnt[c][t+off];
            }
        __syncthreads();
    }
    if (t < NCLS) {
        float ns = fmaxf(cnt[t][0], 1.f);
        g_mu[t][f] = acc[t][0] / ns;
        if (f == 0) { g_cntf[t] = cnt[t][0]; g_ns[t] = ns; }
    }
}

// ---- K3a: deterministic per-segment rank + per-segment class counts ----
__global__ void k_rank(const int* __restrict__ lab) {
    __shared__ int sl[256];
    int seg = blockIdx.x, t = threadIdx.x;
    int n = seg*256 + t;
    int c = lab[n];
    sl[t] = c;
    __syncthreads();
    int rnk = 0, tot = 0;
    for (int i = 0; i < 256; ++i) {
        int e = sl[i];
        if (e == c) { tot += 1; if (i < t) rnk += 1; }
    }
    g_rank[n] = rnk;
    if (rnk == 0) g_segcnt[seg][c] = tot;
}

// ---- K3b: exclusive scan of segment counts per class ----
__global__ void k_segscan() {
    int c = threadIdx.x;
    if (c < NCLS) {
        int run = 0;
        for (int s = 0; s < NSEG; ++s) {
            g_segoff[s][c] = run;
            run += g_segcnt[s][c];
        }
    }
}

// ---- K4: scatter centered features into per-class compacted matrix ----
__global__ void k_scatter(const float* __restrict__ feat, const int* __restrict__ lab) {
    int n = blockIdx.x*256 + threadIdx.x;
    int g = blockIdx.y;
    int c = lab[n];
    int pos = g_segoff[n >> 8][c] + g_rank[n];
    float v = feat[(size_t)(n>>12)*1048576 + (size_t)g*4096 + (n&4095)] - g_mu[c][g];
    g_X[c][g][pos] = v;
}

// ---- K5: cov = (Xc Xc^T)/ns ----
// Dynamic K bound: columns beyond n_c are exact zeros -> truncation is
// bit-identical (R6 win).
__global__ void k_covgemm() {
    int cls = blockIdx.z, ti = blockIdx.y, tj = blockIdx.x;
    __shared__ float At[64][17], Bt[64][17];
    int t = threadIdx.x, tx = t & 15, ty = t >> 4;
    int kc = min(KPAD, (((int)g_cntf[cls]) + 15) & ~15);
    float accv[4][4] = {};
    for (int k0 = 0; k0 < kc; k0 += 16) {
        #pragma unroll
        for (int l = 0; l < 4; ++l) {
            int idx = t*4 + l;
            int row = idx >> 4, col = idx & 15;
            At[row][col] = g_X[cls][ti*64+row][k0+col];
            Bt[row][col] = g_X[cls][tj*64+row][k0+col];
        }
        __syncthreads();
        #pragma unroll
        for (int kk = 0; kk < 16; ++kk) {
            float a[4], b[4];
            #pragma unroll
            for (int i = 0; i < 4; ++i) a[i] = At[ty*4+i][kk];
            #pragma unroll
            for (int j = 0; j < 4; ++j) b[j] = Bt[tx*4+j][kk];
            #pragma unroll
            for (int i = 0; i < 4; ++i)
                #pragma unroll
                for (int j = 0; j < 4; ++j) accv[i][j] += a[i]*b[j];
        }
        __syncthreads();
    }
    float invns = 1.f / g_ns[cls];
    #pragma unroll
    for (int i = 0; i < 4; ++i)
        #pragma unroll
        for (int j = 0; j < 4; ++j)
            g_cov[cls][ti*64+ty*4+i][tj*64+tx*4+j] = accv[i][j]*invns;
}

// ---- K6: FUSED eigensolver, odd-even-transposition (Brent-Luk) ordering ----
// Pairs are ALWAYS adjacent slots: even rounds (2k,2k+1) k=0..127; odd rounds
// (2k+1,2k+2) k=0..126 + fake identity pair 127 covering idle slots {0,255}.
// After every rotation the two labels SWAP (free: swapped write addressing).
// Coverage: 256 rounds x avg 127.5 pairs = C(256,2), each label pair exactly
// once (verified at n=4 by hand). Eigen-sort at the end makes the label
// permutation irrelevant (only (eval, evec) pairs matter).
__global__ __launch_bounds__(1024) void k_eigen() {
    extern __shared__ float smem[];
    int t = threadIdx.x;

    if (blockIdx.x < NCLS) {
        // ================= Jacobi producer =================
        float2* pcs = (float2*)smem;  // 128 packed (c,s)
        float* tri  = smem + 256;     // TRI_N floats (packed triangular)
        int cls = blockIdx.x;

        for (int L = t; L < TRI_N; L += 1024) {
            int i = (int)((sqrtf(8.f*L+1.f)-1.f)*0.5f);
            while ((i+1)*(i+2)/2 <= L) ++i;
            while (i*(i+1)/2 > L) --i;
            int j = L - i*(i+1)/2;
            tri[L] = g_cov[cls][i][j];
        }

        // Fixed-sA group coverage over pair indices 0..127 (unchanged mapping):
        // thread handles groups {sA, sB[k]}, sB = (sA + 8k + h + 1) & 127.
        const int sA = t & 127;
        const int h  = t >> 7;
        const bool k7ok = (h != 7) || (sA < 64);
        int sB[8];
        #pragma unroll
        for (int k = 0; k < 8; ++k) sB[k] = (sA + 8*k + h + 1) & 127;
        __syncthreads();

        for (int step = 0; step < NSTEP2; ++step) {
            const bool odd = (step & 1) != 0;
            if (t < NPAIR) {
                const bool fake = odd && (t == 127);
                float c = 1.f, s = 0.f;
                int p = 0;
                float app = 0.f, aqq = 0.f, apq = 0.f;
                int dq = 0;
                if (!fake) {
                    p = odd ? 2*t + 1 : 2*t;          // q = p+1
                    dq = tidx(p + 1, p);               // (q,p); (q,q)=dq+1
                    app = tri[tidx(p, p)];
                    apq = tri[dq];
                    aqq = tri[dq + 1];
                    if (fabsf(apq) > 1e-30f) {
                        float theta = (aqq - app) / (2.f*apq);
                        float tt = 1.f/(fabsf(theta) + sqrtf(theta*theta + 1.f));
                        if (theta < 0.f) tt = -tt;
                        c = 1.f/sqrtf(tt*tt + 1.f);
                        s = tt*c;
                    }
                }
                PackCS pk; pk.f = make_float2(c, s);
                __hip_atomic_store(&g_rotlog[cls][step][t], pk.u,
                                   __ATOMIC_RELAXED, __HIP_MEMORY_SCOPE_AGENT);
                pcs[t] = make_float2(c, s);
                if (!fake) {
                    float napp = c*c*app - 2.f*c*s*apq + s*s*aqq;
                    float naqq = s*s*app + 2.f*c*s*apq + c*c*aqq;
                    // label swap: slot p gets the (old q)-label's new diag
                    tri[tidx(p, p)] = naqq;
                    tri[dq + 1]     = napp;
                    tri[dq]         = 0.f;
                }
            }
            __syncthreads();   // pcs + diag/swap updates visible

            float2 csA = pcs[sA];
            #pragma unroll
            for (int k = 0; k < 8; ++k) {
                if (k == 7 && !k7ok) continue;
                int v = sB[k];
                float2 csB = pcs[v];
                bool sw = v < sA;
                int hi = sw ? sA : v;
                int lo = sw ? v : sA;
                float c1 = sw ? csA.x : csB.x, s1 = sw ? csA.y : csB.y; // rows (hi)
                float c2 = sw ? csB.x : csA.x, s2 = sw ? csB.y : csA.y; // cols (lo)
                if (odd && hi == 127) {
                    // fake group: slots {0,255} x real pair lo (2lo+1, 2lo+2).
                    // Identity on the fake side; only lo's rotation applies.
                    int cc = 2*lo + 1;
                    int b2 = tidx(255, cc);           // (255,cc),(255,cc+1)
                    float B0 = tri[b2], B1 = tri[b2+1];
                    int r0 = tidx(cc, 0);
                    int r1 = r0 + cc + 1;             // tidx(cc+1, 0)
                    float C0 = tri[r0], C1 = tri[r1];
                    float Y0 = c2*B0 - s2*B1, Y1 = s2*B0 + c2*B1; // col-rotate
                    float Z0 = c2*C0 - s2*C1, Z1 = s2*C0 + c2*C1; // row-rotate
                    tri[b2] = Y1; tri[b2+1] = Y0;                 // col-swap
                    tri[r0] = Z1; tri[r1] = Z0;                   // row-swap
                    continue;
                }
                int rp = odd ? 2*hi + 1 : 2*hi;       // row slots rp, rp+1
                int cc = odd ? 2*lo + 1 : 2*lo;       // col slots cc, cc+1
                int b0 = tidx(rp, cc);                // (rp,cc),(rp,cc+1)
                int b1 = b0 + rp + 1;                 // (rp+1,cc),(rp+1,cc+1)
                float B00 = tri[b0], B01 = tri[b0+1];
                float B10 = tri[b1], B11 = tri[b1+1];
                float X00 = c1*B00 - s1*B10, X01 = c1*B01 - s1*B11;
                float X10 = s1*B00 + c1*B10, X11 = s1*B01 + c1*B11;
                float Y00 = c2*X00 - s2*X01, Y01 = s2*X00 + c2*X01;
                float Y10 = c2*X10 - s2*X11, Y11 = s2*X10 + c2*X11;
                // both pairs swap labels -> fully swapped write-back
                tri[b0] = Y11; tri[b0+1] = Y10;
                tri[b1] = Y01; tri[b1+1] = Y00;
            }
            __syncthreads();   // drains rotlog store + all LDS
            if (t == 0) {
                __hip_atomic_store(&g_step[cls*FLAGSTRIDE], step+1,
                                   __ATOMIC_RELAXED, __HIP_MEMORY_SCOPE_AGENT);
            }
        }
        // publish eigenvalues then release final flag
        for (int f = t; f < FDIM; f += 1024) {
            PackF pf; pf.f = tri[tidx(f,f)];
            __hip_atomic_store((unsigned int*)&g_eval[cls][f], pf.u,
                               __ATOMIC_RELAXED, __HIP_MEMORY_SCOPE_AGENT);
        }
        __syncthreads();
        if (t == 0) {
            __hip_atomic_store(&g_step[cls*FLAGSTRIDE], NSTEP2+1,
                               __ATOMIC_RELAXED, __HIP_MEMORY_SCOPE_AGENT);
        }
    } else {
        // ======= eigenvector consumer (+ fused sort / W write) =======
        float2* lcs = (float2*)smem;            // 128 packed (c,s)
        float* st = smem + 256;                 // 256 x VST state (64 V-columns)
        float* evbuf = smem + 256 + 256*VST;    // 256 eigenvalues
        int*   rkbuf = (int*)(evbuf + 256);     // 256 ranks
        int rb = blockIdx.x - NCLS;
        int cls = rb >> 2;
        int ibase = (rb & 3) * 64;

        for (int idx = t; idx < 256*64; idx += 1024) {
            int p = idx >> 6, col = idx & 63;
            st[p*VST + col] = (p == ibase + col) ? 1.f : 0.f;
        }

        int s0 = t >> 5;
        int cp = t & 31;
        __syncthreads();

        for (int step = 0; step < NSTEP2; ++step) {
            if (t == 0) {
                while (__hip_atomic_load(&g_step[cls*FLAGSTRIDE], __ATOMIC_RELAXED,
                                         __HIP_MEMORY_SCOPE_AGENT) <= step)
                    __builtin_amdgcn_s_sleep(2);
            }
            __syncthreads();
            if (t < NPAIR) {
                PackCS pk;
                pk.u = __hip_atomic_load(&g_rotlog[cls][step][t],
                                         __ATOMIC_RELAXED, __HIP_MEMORY_SCOPE_AGENT);
                lcs[t] = pk.f;
            }
            __syncthreads();
            const bool odd = (step & 1) != 0;
            float2 xv[4], yv[4];
            float cv[4], sv[4];
            int pa[4];
            bool act[4];
            #pragma unroll
            for (int w = 0; w < 4; ++w) {
                int s = s0 + 32*w;
                act[w] = !(odd && s == 127);
                float2 cs = lcs[s];
                cv[w] = cs.x; sv[w] = cs.y;
                pa[w] = odd ? 2*s + 1 : 2*s;
                if (act[w]) {
                    xv[w] = *(float2*)&st[pa[w]*VST + 2*cp];
                    yv[w] = *(float2*)&st[(pa[w]+1)*VST + 2*cp];
                }
            }
            #pragma unroll
            for (int w = 0; w < 4; ++w) {
                if (!act[w]) continue;
                float2 nx, ny;
                nx.x = cv[w]*xv[w].x - sv[w]*yv[w].x;
                nx.y = cv[w]*xv[w].y - sv[w]*yv[w].y;
                ny.x = sv[w]*xv[w].x + cv[w]*yv[w].x;
                ny.y = sv[w]*xv[w].y + cv[w]*yv[w].y;
                // label swap mirrors producer
                *(float2*)&st[pa[w]*VST + 2*cp]     = ny;
                *(float2*)&st[(pa[w]+1)*VST + 2*cp] = nx;
            }
        }
        // wait for eigenvalues, rank, write W (slot-space is consistent
        // between eval[] and st rows; sort pairs them by value)
        if (t == 0) {
            while (__hip_atomic_load(&g_step[cls*FLAGSTRIDE], __ATOMIC_RELAXED,
                                     __HIP_MEMORY_SCOPE_AGENT) <= NSTEP2)
                __builtin_amdgcn_s_sleep(2);
        }
        __syncthreads();
        if (t < 256) {
            PackF pf;
            pf.u = __hip_atomic_load((unsigned int*)&g_eval[cls][t],
                                     __ATOMIC_RELAXED, __HIP_MEMORY_SCOPE_AGENT);
            evbuf[t] = pf.f;
        }
        __syncthreads();
        if (t < 256) {
            float mine = evbuf[t];
            int r = 0;
            for (int f = 0; f < 256; ++f) {
                float o = evbuf[f];
                if (o > mine || (o == mine && f < t)) ++r;
            }
            rkbuf[t] = r;
        }
        __syncthreads();
        for (int idx = t; idx < 256*32; idx += 1024) {
            int f = idx >> 5, c2 = idx & 31;
            float2 v = *(float2*)&st[f*VST + 2*c2];
            *(float2*)&g_W[cls][rkbuf[f]][ibase + 2*c2] = v;
        }
    }
}

// ---- K10: M[c] = proj @ W[c]   (D x F) ----
__global__ void k_mgemm(const float* __restrict__ pm) {
    int cls = blockIdx.z, dt = blockIdx.y, gt = blockIdx.x;
    __shared__ float At[64][17], Bt[16][65];
    int t = threadIdx.x, tx = t & 15, ty = t >> 4;
    float accv[4][4] = {};
    for (int k0 = 0; k0 < FDIM; k0 += 16) {
        #pragma unroll
        for (int l = 0; l < 4; ++l) {
            int idx = t*4 + l;
            int row = idx >> 4, col = idx & 15;
            At[row][col] = pm[(size_t)(dt*64+row)*FDIM + k0 + col];
        }
        #pragma unroll
        for (int l = 0; l < 4; ++l) {
            int idx = t*4 + l;
            int row = idx >> 6, col = idx & 63;
            Bt[row][col] = g_W[cls][k0+row][gt*64+col];
        }
        __syncthreads();
        #pragma unroll
        for (int kk = 0; kk < 16; ++kk) {
            float a[4], b[4];
            #pragma unroll
            for (int i = 0; i < 4; ++i) a[i] = At[ty*4+i][kk];
            #pragma unroll
            for (int j = 0; j < 4; ++j) b[j] = Bt[kk][tx*4+j];
            #pragma unroll
            for (int i = 0; i < 4; ++i)
                #pragma unroll
                for (int j = 0; j < 4; ++j) accv[i][j] += a[i]*b[j];
        }
        __syncthreads();
    }
    #pragma unroll
    for (int i = 0; i < 4; ++i)
        #pragma unroll
        for (int j = 0; j < 4; ++j)
            g_M[cls][dt*64+ty*4+i][gt*64+tx*4+j] = accv[i][j];
}

// ---- K11: fv = M[c] @ Xc, accumulate moments m1..m4 over columns ----
// Dynamic K bound (R6): zero tail is bit-identical to skip.
__global__ void k_fvmom() {
    int cls = blockIdx.y, dt = blockIdx.x;
    __shared__ float Mt[64][17], Xt[16][65];
    __shared__ float red[64][16];
    int t = threadIdx.x, tx = t & 15, ty = t >> 4;
    int kc = min(KPAD, (((int)g_cntf[cls]) + 63) & ~63);
    float mm[4][4] = {};
    for (int kt = 0; kt < kc; kt += 64) {
        float accv[4][4] = {};
        for (int g0 = 0; g0 < FDIM; g0 += 16) {
            #pragma unroll
            for (int l = 0; l < 4; ++l) {
                int idx = t*4 + l;
                int row = idx >> 4, col = idx & 15;
                Mt[row][col] = g_M[cls][dt*64+row][g0+col];
            }
            #pragma unroll
            for (int l = 0; l < 4; ++l) {
                int idx = t*4 + l;
                int row = idx >> 6, col = idx & 63;
                Xt[row][col] = g_X[cls][g0+row][kt+col];
            }
            __syncthreads();
            #pragma unroll
            for (int kk = 0; kk < 16; ++kk) {
                float a[4], b[4];
                #pragma unroll
                for (int i = 0; i < 4; ++i) a[i] = Mt[ty*4+i][kk];
                #pragma unroll
                for (int j = 0; j < 4; ++j) b[j] = Xt[kk][tx*4+j];
                #pragma unroll
                for (int i = 0; i < 4; ++i)
                    #pragma unroll
                    for (int j = 0; j < 4; ++j) accv[i][j] += a[i]*b[j];
            }
            __syncthreads();
        }
        #pragma unroll
        for (int i = 0; i < 4; ++i)
            #pragma unroll
            for (int j = 0; j < 4; ++j) {
                float v = accv[i][j], v2 = v*v;
                mm[0][i] += v; mm[1][i] += v2; mm[2][i] += v2*v; mm[3][i] += v2*v2;
            }
    }
    #pragma unroll
    for (int m = 0; m < 4; ++m) {
        __syncthreads();
        #pragma unroll
        for (int i = 0; i < 4; ++i) red[ty*4+i][tx] = mm[m][i];
        __syncthreads();
        if (t < 64) {
            float s = 0.f;
            #pragma unroll
            for (int x = 0; x < 16; ++x) s += red[t][x];
            g_mom[cls][dt*64 + t][m] = s;
        }
    }
}

// ---- K12: kurtosis, clip, weighted mean -> loss ----
__global__ __launch_bounds__(1024) void k_loss(float* __restrict__ out) {
    __shared__ float red[1024];
    int t = threadIdx.x;
    float sum = 0.f;
    for (int id = t; id < NCLS*DDIR; id += 1024) {
        int c = id >> 10, d = id & 1023;
        float cntv = g_cntf[c];
        if (cntv > 0.f) {
            float invns = 1.f / g_ns[c];
            float m1 = g_mom[c][d][0]*invns;
            float m2 = g_mom[c][d][1]*invns;
            float m3 = g_mom[c][d][2]*invns;
            float m4 = g_mom[c][d][3]*invns;
            float var = fmaxf(m2 - m1*m1, 1e-16f);
            float m4c = -3.f*m1*m1*m1*m1 + 6.f*m2*m1*m1 - 4.f*m3*m1 + m4;
            float kurt = m4c/(var*var) - 3.f;
            kurt = fminf(fmaxf(kurt, -3.f), 3.f);
            sum += kurt*kurt;
        }
    }
    red[t] = sum;
    __syncthreads();
    for (int off = 512; off > 0; off >>= 1) {
        if (t < off) red[t] += red[t+off];
        __syncthreads();
    }
    if (t == 0) {
        float na = 0.f;
        for (int c = 0; c < NCLS; ++c) na += (g_cntf[c] > 0.f) ? 1.f : 0.f;
        na = fmaxf(na, 1.f);
        out[0] = red[0] / ((float)DDIR * na);
    }
}

extern "C" void kernel_launch(void* const* d_in, const int* in_sizes, int n_in,
                              void* d_out, int out_size, void* d_ws, size_t ws_size,
                              hipStream_t stream) {
    const float* feat = (const float*)d_in[0];
    const int*   lab  = (const int*)d_in[1];
    const float* pm   = (const float*)d_in[2];
    float* out = (float*)d_out;

    const int eig_lds = (256 + TRI_N) * 4 + 64;   // producer needs the max

    (void)hipFuncSetAttribute((const void*)k_eigen,
        hipFuncAttributeMaxDynamicSharedMemorySize, eig_lds);

    hipLaunchKernelGGL(k_zero, dim3(3648), dim3(1024), 0, stream);
    hipLaunchKernelGGL(k_sums, dim3(256), dim3(256), 0, stream, feat, lab);
    hipLaunchKernelGGL(k_rank, dim3(NSEG), dim3(256), 0, stream, lab);
    hipLaunchKernelGGL(k_segscan, dim3(1), dim3(64), 0, stream);
    hipLaunchKernelGGL(k_scatter, dim3(32, 256), dim3(256), 0, stream, feat, lab);
    hipLaunchKernelGGL(k_covgemm, dim3(4, 4, NCLS), dim3(256), 0, stream);
    hipLaunchKernelGGL(k_eigen, dim3(NCLS + NCLS*4), dim3(1024), eig_lds, stream);
    hipLaunchKernelGGL(k_mgemm, dim3(4, 16, NCLS), dim3(256), 0, stream, pm);
    hipLaunchKernelGGL(k_fvmom, dim3(16, NCLS), dim3(256), 0, stream);
    hipLaunchKernelGGL(k_loss, dim3(1), dim3(1024), 0, stream, out);
}